// Round 1
// baseline (34850.873 us; speedup 1.0000x reference)
//
#include <hip/hip_runtime.h>
#include <math.h>

// ---------------- problem constants ----------------
#define NN 512
#define EE 2048
#define IN_F 64
#define HID 256
#define MSGD 128
#define OUTC 16
#define PPD 4
#define MAX_STEPS 5120

// ---------------- kernel config ----------------
#define NWG 16                 // workgroups in persistent kernel
#define TPB 512                // threads per WG
#define UPW (HID / NWG)        // 16 hidden units per WG
#define GROWS (4 * UPW)        // 64 gate rows per WG
#define MPW (MSGD / NWG)       // 8 msg cols per WG (for nm partial)

// ---------------- device globals (scratch; re-initialized every call) ----------------
__device__ int   g_nbrs[NN][NN];          // sorted unique neighbor lists
__device__ int   g_degs[NN];
__device__ int4  g_sched[MAX_STEPS];      // x=node, y=t(enqueue base), z=deg, w=flags(bit0 active, bit1 same-as-prev)
__device__ float g_qmsgs[MAX_STEPS][MSGD];
__device__ float g_hid[NN][HID];
__device__ float g_cell[NN][HID];
__device__ float g_hnew[2][HID];          // per-step-parity full h_new broadcast
__device__ float g_partials[2][NWG][MSGD];
__device__ int   g_bar_cnt;
__device__ int   g_bar_gen;

__device__ __forceinline__ float sigm(float x) { return 1.0f / (1.0f + expf(-x)); }

// agent-scope grid barrier for NWG co-resident workgroups
__device__ __forceinline__ void grid_barrier() {
    __syncthreads();
    // make this wave's prior global stores visible device-wide (per-XCD L2 writeback)
    __builtin_amdgcn_fence(__ATOMIC_RELEASE, "agent");
    if (threadIdx.x == 0) {
        int gen = __hip_atomic_load(&g_bar_gen, __ATOMIC_RELAXED, __HIP_MEMORY_SCOPE_AGENT);
        int arrived = __hip_atomic_fetch_add(&g_bar_cnt, 1, __ATOMIC_ACQ_REL, __HIP_MEMORY_SCOPE_AGENT);
        if (arrived == NWG - 1) {
            __hip_atomic_store(&g_bar_cnt, 0, __ATOMIC_RELAXED, __HIP_MEMORY_SCOPE_AGENT);
            __hip_atomic_fetch_add(&g_bar_gen, 1, __ATOMIC_RELEASE, __HIP_MEMORY_SCOPE_AGENT);
        } else {
            while (__hip_atomic_load(&g_bar_gen, __ATOMIC_RELAXED, __HIP_MEMORY_SCOPE_AGENT) == gen) {
                __builtin_amdgcn_s_sleep(1);
            }
        }
    }
    __syncthreads();
    // invalidate stale cached lines before subsequent loads
    __builtin_amdgcn_fence(__ATOMIC_ACQUIRE, "agent");
}

// ---------------- kernel A: encoder hid = xa @ enc_W^T + enc_b ; cell = 0 ----------------
__global__ __launch_bounds__(256) void k_encoder(const float* __restrict__ xa,
                                                 const float* __restrict__ enc_W,
                                                 const float* __restrict__ enc_b) {
    int gid = blockIdx.x * 256 + threadIdx.x;   // grid 512 -> 131072 = 512*256 outputs
    int n = gid >> 8, c = gid & 255;
    const float* x = xa + n * IN_F;
    const float* w = enc_W + c * IN_F;
    float acc = enc_b[c];
#pragma unroll 8
    for (int j = 0; j < IN_F; ++j) acc += x[j] * w[j];
    g_hid[n][c] = acc;
    g_cell[n][c] = 0.0f;
}

// ---------------- kernel B: graph prep + full schedule precompute ----------------
// Single block, 1024 threads. The processing order is message-independent:
// q_nodes / t / active depend only on graph + starts.
__global__ __launch_bounds__(1024) void k_graph(const int* __restrict__ edge_index,
                                                const int* __restrict__ starts,
                                                const float* __restrict__ first_message) {
    __shared__ unsigned int bm[NN * 16];     // 512x512 adjacency bitmap (32KB)
    __shared__ int s_nodes[NN];
    __shared__ int scanbuf[2][1024];
    __shared__ int sh_misc[4];
    const int tid = threadIdx.x;

    for (int i = tid; i < NN * 16; i += 1024) bm[i] = 0u;
    __syncthreads();
    for (int e = tid; e < EE; e += 1024) {
        int s = edge_index[e], d = edge_index[EE + e];
        atomicOr(&bm[s * 16 + (d >> 5)], 1u << (d & 31));
        atomicOr(&bm[d * 16 + (s >> 5)], 1u << (s & 31));
    }
    __syncthreads();
    if (tid < NN) {
        int cnt = 0;
        for (int w = 0; w < 16; ++w) {
            unsigned int bits = bm[tid * 16 + w];
            while (bits) {
                int b = __ffs(bits) - 1;
                bits &= bits - 1u;
                g_nbrs[tid][cnt++] = w * 32 + b;   // ascending => sorted set
            }
        }
        g_degs[tid] = cnt;
    }
    if (tid == 0) {
        int s0 = 0;
        for (int n = 0; n < NN; ++n) if (starts[n] != 0) s_nodes[s0++] = n;
        sh_misc[0] = s0;
    }
    __syncthreads();
    const int S0 = sh_misc[0];
    int known = (S0 < MAX_STEPS) ? S0 : MAX_STEPS;
    for (int i = tid; i < known; i += 1024) g_sched[i].x = s_nodes[i];
    for (int idx = tid; idx < known * MSGD; idx += 1024) {
        int i = idx >> 7, o = idx & (MSGD - 1);
        g_qmsgs[i][o] = first_message[s_nodes[i] * MSGD + o];
    }
    __syncthreads();

    // round-expansion of the queue schedule (assume all-active; cut at istar below)
    for (int round = 0; round < 8 && known > 0; ++round) {
        const int C = (known + 1023) >> 10;
        const int base = tid * C;
        int lsum = 0;
        for (int j = 0; j < C; ++j) {
            int i = base + j;
            if (i < known) lsum += g_degs[g_sched[i].x];
        }
        scanbuf[0][tid] = lsum;
        __syncthreads();
        int src = 0;
        for (int off = 1; off < 1024; off <<= 1) {
            int v = scanbuf[src][tid];
            if (tid >= off) v += scanbuf[src][tid - off];
            scanbuf[src ^ 1][tid] = v;
            src ^= 1;
            __syncthreads();
        }
        const int excl = (tid == 0) ? 0 : scanbuf[src][tid - 1];
        const int total = scanbuf[src][1023];
        int t = S0 + excl;
        for (int j = 0; j < C; ++j) {
            int i = base + j;
            if (i < known) {
                int nd = g_sched[i].x;
                int dg = g_degs[nd];
                g_sched[i].y = t;
                g_sched[i].z = dg;
                for (int e = 0; e < dg; ++e) {
                    int pos = t + e;
                    if (pos >= known && pos < MAX_STEPS) g_sched[pos].x = g_nbrs[nd][e];
                }
                t += dg;
            }
        }
        __syncthreads();
        int newknown = S0 + total;
        if (newknown > MAX_STEPS) newknown = MAX_STEPS;
        if (newknown == known) break;      // queue drained (or fully filled)
        known = newknown;
    }
    __syncthreads();
    const int kn = known;
    if (tid == 0) sh_misc[1] = kn;
    __syncthreads();
    for (int i = tid; i < kn; i += 1024) {
        if (g_sched[i].y <= i) atomicMin(&sh_misc[1], i);   // first drained step
    }
    __syncthreads();
    const int istar = sh_misc[1];
    for (int i = tid; i < MAX_STEPS; i += 1024) {
        int4 sc;
        if (i < kn) sc = g_sched[i];
        else { sc.x = 0; sc.y = 0x7fffffff; sc.z = 0; }
        int fl = 0;
        if (i < istar) {
            fl = 1;
            if (i > 0 && (i - 1) < istar && g_sched[i - 1].x == sc.x) fl |= 2;
        }
        sc.w = fl;
        g_sched[i] = sc;
    }
    if (tid == 0) { g_bar_cnt = 0; g_bar_gen = 0; }
}

// ---------------- main persistent kernel ----------------
__global__ __launch_bounds__(TPB, 1) void k_main(const float* __restrict__ W_ih,
                                                 const float* __restrict__ W_hh,
                                                 const float* __restrict__ b_ih,
                                                 const float* __restrict__ b_hh,
                                                 const float* __restrict__ nm_W,
                                                 const float* __restrict__ nm_b,
                                                 const float* __restrict__ dec_W,
                                                 const float* __restrict__ dec_b,
                                                 float* __restrict__ out) {
    // LDS: weight slices padded so access c = sub + 8*j is bank-conflict-free
    __shared__ float sWih[GROWS][136];   // stride 136 % 32 == 8 -> 2 lanes/bank (free)
    __shared__ float sWhh[GROWS][264];   // stride 264 % 32 == 8
    __shared__ float sNmH[MSGD][17];     // odd stride -> free
    __shared__ float sNmM[MSGD][9];
    __shared__ float sBias[GROWS];
    __shared__ float sNmB[MSGD];
    __shared__ float sAct[MSGD + HID];
    __shared__ float sGates[GROWS];
    __shared__ float sHnew[UPW];

    const int tid = threadIdx.x;
    const int wg  = blockIdx.x;

    // ---- one-time weight slice load: local row r = gate*UPW+u <-> global G = gate*HID + wg*UPW + u
    for (int idx = tid; idx < GROWS * MSGD; idx += TPB) {
        int r = idx >> 7, c = idx & (MSGD - 1);
        int G = (r / UPW) * HID + wg * UPW + (r % UPW);
        sWih[r][c] = W_ih[G * MSGD + c];
    }
    for (int idx = tid; idx < GROWS * HID; idx += TPB) {
        int r = idx >> 8, c = idx & (HID - 1);
        int G = (r / UPW) * HID + wg * UPW + (r % UPW);
        sWhh[r][c] = W_hh[G * HID + c];
    }
    if (tid < GROWS) {
        int G = (tid / UPW) * HID + wg * UPW + (tid % UPW);
        sBias[tid] = b_ih[G] + b_hh[G];
    }
    for (int idx = tid; idx < MSGD * UPW; idx += TPB) {
        int o = idx / UPW, u = idx % UPW;
        sNmH[o][u] = nm_W[o * (HID + MSGD) + wg * UPW + u];
    }
    for (int idx = tid; idx < MSGD * MPW; idx += TPB) {
        int o = idx / MPW, m = idx % MPW;
        sNmM[o][m] = nm_W[o * (HID + MSGD) + HID + wg * MPW + m];
    }
    if (tid < MSGD) sNmB[tid] = nm_b[tid];
    __syncthreads();

    float hn_reg = 0.0f, cn_reg = 0.0f;   // my h/c slice element (thread u<UPW) of previous step
    int prev_node = 0, prev_t = 0, prev_deg = 0;
    bool prev_active = false;

    for (int i = 0; i < MAX_STEPS; ++i) {
        const int4 sc = g_sched[i];
        const int node = sc.x, tpos = sc.y;
        const bool active = (sc.w & 1) != 0;
        const bool same   = (sc.w & 2) != 0;   // node == node_{i-1} && step i-1 active
        const int par = i & 1, pp = par ^ 1;

        // Phase 1: apply previous step's h/c to canonical state (deferred one step;
        // concurrent readers of the same row are diverted via 'same')
        if (prev_active && tid < UPW) {
            const int gu = wg * UPW + tid;
            g_hid[prev_node][gu]  = hn_reg;
            g_cell[prev_node][gu] = cn_reg;
        }
        // Phase 2: WG0 finalizes previous step's outgoing message and enqueues it.
        // Safe: message at position q is read at step q >= t_{i-1} >= S0 + i - 1 >> i.
        if (wg == 0 && prev_active && prev_t < MAX_STEPS && tid < MSGD) {
            float m = sNmB[tid];
#pragma unroll
            for (int kk = 0; kk < NWG; ++kk) m += g_partials[pp][kk][tid];
            const int lim = (prev_t + prev_deg <= MAX_STEPS) ? prev_deg : (MAX_STEPS - prev_t);
            for (int e = 0; e < lim; ++e) g_qmsgs[prev_t + e][tid] = m;
        }
        // Phase 3: stage activation [msg(128) | h_prev(256)]
        if (active && tid < MSGD + HID) {
            const int c = tid;
            sAct[c] = (c < MSGD) ? g_qmsgs[i][c]
                                 : (same ? g_hnew[pp][c - MSGD] : g_hid[node][c - MSGD]);
        }
        __syncthreads();
        // Phase 4: 64 gate rows, 384-dot each; 8 lanes per row
        if (active) {
            const int r = tid >> 3, sub = tid & 7;
            float a0 = 0.0f, a1 = 0.0f;
#pragma unroll
            for (int j = 0; j < 16; j += 2) {
                a0 += sWih[r][sub + 8 * j]       * sAct[sub + 8 * j];
                a1 += sWih[r][sub + 8 * (j + 1)] * sAct[sub + 8 * (j + 1)];
            }
#pragma unroll
            for (int j = 0; j < 32; j += 2) {
                a0 += sWhh[r][sub + 8 * j]       * sAct[MSGD + sub + 8 * j];
                a1 += sWhh[r][sub + 8 * (j + 1)] * sAct[MSGD + sub + 8 * (j + 1)];
            }
            float acc = a0 + a1;
            acc += __shfl_xor(acc, 1);
            acc += __shfl_xor(acc, 2);
            acc += __shfl_xor(acc, 4);
            if (sub == 0) sGates[r] = acc + sBias[r];
        }
        __syncthreads();
        // Phase 5: LSTM cell update for my 16-unit slice (torch gate order i,f,g,o)
        if (active && tid < UPW) {
            const int u = tid, gu = wg * UPW + u;
            const float gi = sGates[u];
            const float gf = sGates[UPW + u];
            const float gg = sGates[2 * UPW + u];
            const float go = sGates[3 * UPW + u];
            const float cp = same ? cn_reg : g_cell[node][gu];
            const float cn = sigm(gf) * cp + sigm(gi) * tanhf(gg);
            const float hn = sigm(go) * tanhf(cn);
            g_hnew[par][gu] = hn;
            sHnew[u] = hn;
            hn_reg = hn; cn_reg = cn;
        }
        __syncthreads();
        // Phase 6: partial of the outgoing message (skip if enqueue fully out of range)
        if (active && tpos < MAX_STEPS && tid < MSGD) {
            float a = 0.0f;
#pragma unroll
            for (int u = 0; u < UPW; ++u) a += sNmH[tid][u] * sHnew[u];
#pragma unroll
            for (int m = 0; m < MPW; ++m) a += sNmM[tid][m] * sAct[wg * MPW + m];
            g_partials[par][wg][tid] = a;
        }
        if (active) { prev_node = node; prev_t = tpos; prev_deg = sc.z; }
        prev_active = active;
        grid_barrier();
    }

    // apply the last step's h (cell not needed for output)
    if (prev_active && tid < UPW) {
        g_hid[prev_node][wg * UPW + tid] = hn_reg;
    }
    grid_barrier();

    // ---- decoder: logits[p,n,o] = hid[n,:] . dec_W[p,o,:] + dec_b[p,o]; log_softmax over o
    const int gtid = wg * TPB + tid;
    const int grp = gtid >> 4, lane = gtid & 15;
    for (int rep = 0; rep < 4; ++rep) {
        const int row = grp * 4 + rep;             // row = p*NN + n, 0..2047
        const int p = row >> 9, n = row & (NN - 1);
        const float* w = dec_W + (p * OUTC + lane) * HID;
        float acc = dec_b[p * OUTC + lane];
#pragma unroll 4
        for (int h = 0; h < HID; ++h) acc += g_hid[n][h] * w[h];
        float mx = acc;
        mx = fmaxf(mx, __shfl_xor(mx, 1));
        mx = fmaxf(mx, __shfl_xor(mx, 2));
        mx = fmaxf(mx, __shfl_xor(mx, 4));
        mx = fmaxf(mx, __shfl_xor(mx, 8));
        float s = expf(acc - mx);
        s += __shfl_xor(s, 1);
        s += __shfl_xor(s, 2);
        s += __shfl_xor(s, 4);
        s += __shfl_xor(s, 8);
        out[row * OUTC + lane] = acc - mx - logf(s);
    }
}

extern "C" void kernel_launch(void* const* d_in, const int* in_sizes, int n_in,
                              void* d_out, int out_size, void* d_ws, size_t ws_size,
                              hipStream_t stream) {
    (void)in_sizes; (void)n_in; (void)out_size; (void)d_ws; (void)ws_size;
    const float* xa   = (const float*)d_in[0];
    const float* fm   = (const float*)d_in[1];
    const int*   ei   = (const int*)d_in[2];
    const int*   st   = (const int*)d_in[3];
    const float* encW = (const float*)d_in[4];
    const float* encb = (const float*)d_in[5];
    const float* Wih  = (const float*)d_in[6];
    const float* Whh  = (const float*)d_in[7];
    const float* bih  = (const float*)d_in[8];
    const float* bhh  = (const float*)d_in[9];
    const float* nmW  = (const float*)d_in[10];
    const float* nmb  = (const float*)d_in[11];
    const float* decW = (const float*)d_in[12];
    const float* decb = (const float*)d_in[13];
    float* out = (float*)d_out;

    hipLaunchKernelGGL(k_encoder, dim3(512), dim3(256), 0, stream, xa, encW, encb);
    hipLaunchKernelGGL(k_graph,   dim3(1),   dim3(1024), 0, stream, ei, st, fm);
    hipLaunchKernelGGL(k_main,    dim3(NWG), dim3(TPB), 0, stream,
                       Wih, Whh, bih, bhh, nmW, nmb, decW, decb, out);
}

// Round 2
// 12076.521 us; speedup vs baseline: 2.8858x; 2.8858x over previous
//
#include <hip/hip_runtime.h>
#include <math.h>

// ---------------- problem constants ----------------
#define NN 512
#define EE 2048
#define IN_F 64
#define HID 256
#define MSGD 128
#define OUTC 16
#define PPD 4
#define MAX_STEPS 5120

// ---------------- kernel config ----------------
#define NGROUP 8               // step-parallel groups
#define NWG 16                 // slice-WGs per group (HID split)
#define NWGTOT (NGROUP * NWG)  // 128 workgroups total
#define TPB 512                // threads per WG
#define UPW (HID / NWG)        // 16 hidden units per slice
#define GROWS (4 * UPW)        // 64 gate rows per slice
#define MPW (MSGD / NWG)       // 8 msg cols per slice (nm partial)
#define BMAX 64                // max steps per batch
#define PSLOTS 128             // partials ring (>= 2*BMAX)

// ---------------- device globals (all re-initialized every call) ----------------
__device__ int   g_nbrs[NN][NN];
__device__ int   g_degs[NN];
__device__ int4  g_sched[MAX_STEPS];        // x=node, y=t(enqueue base), z=deg, w=unused
__device__ int   g_prod[MAX_STEPS];         // producer step of each queue position (-1 = initial)
__device__ int   g_bid[MAX_STEPS];          // batch id per step
__device__ int   g_bstart[2 * MAX_STEPS + 2];
__device__ int   g_nbatch;
__device__ float g_qmsgs[MAX_STEPS][MSGD];
__device__ float g_hid[NN][HID];
__device__ float g_cell[NN][HID];
__device__ float g_partials[PSLOTS][NWG][MSGD];
__device__ int   g_bar_cnt;
__device__ int   g_bar_gen;

__device__ __forceinline__ float sigm(float x) { return 1.0f / (1.0f + expf(-x)); }

// agent-scope grid barrier for NWGTOT co-resident workgroups
__device__ __forceinline__ void grid_barrier() {
    __syncthreads();
    __builtin_amdgcn_fence(__ATOMIC_RELEASE, "agent");
    if (threadIdx.x == 0) {
        int gen = __hip_atomic_load(&g_bar_gen, __ATOMIC_RELAXED, __HIP_MEMORY_SCOPE_AGENT);
        int arrived = __hip_atomic_fetch_add(&g_bar_cnt, 1, __ATOMIC_ACQ_REL, __HIP_MEMORY_SCOPE_AGENT);
        if (arrived == NWGTOT - 1) {
            __hip_atomic_store(&g_bar_cnt, 0, __ATOMIC_RELAXED, __HIP_MEMORY_SCOPE_AGENT);
            __hip_atomic_fetch_add(&g_bar_gen, 1, __ATOMIC_RELEASE, __HIP_MEMORY_SCOPE_AGENT);
        } else {
            while (__hip_atomic_load(&g_bar_gen, __ATOMIC_RELAXED, __HIP_MEMORY_SCOPE_AGENT) == gen) {
                __builtin_amdgcn_s_sleep(1);
            }
        }
    }
    __syncthreads();
    __builtin_amdgcn_fence(__ATOMIC_ACQUIRE, "agent");
}

// ---------------- kernel A: encoder ----------------
__global__ __launch_bounds__(256) void k_encoder(const float* __restrict__ xa,
                                                 const float* __restrict__ enc_W,
                                                 const float* __restrict__ enc_b) {
    int gid = blockIdx.x * 256 + threadIdx.x;
    int n = gid >> 8, c = gid & 255;
    const float* x = xa + n * IN_F;
    const float* w = enc_W + c * IN_F;
    float acc = enc_b[c];
#pragma unroll 8
    for (int j = 0; j < IN_F; ++j) acc += x[j] * w[j];
    g_hid[n][c] = acc;
    g_cell[n][c] = 0.0f;
}

// ---------------- kernel B: graph prep + schedule + batch construction ----------------
__global__ __launch_bounds__(1024) void k_graph(const int* __restrict__ edge_index,
                                                const int* __restrict__ starts,
                                                const float* __restrict__ first_message) {
    __shared__ unsigned int bm[NN * 16];
    __shared__ int s_nodes[NN];
    __shared__ int scanbuf[2][1024];
    __shared__ int sh_misc[4];
    const int tid = threadIdx.x;

    for (int i = tid; i < NN * 16; i += 1024) bm[i] = 0u;
    for (int i = tid; i < MAX_STEPS; i += 1024) g_prod[i] = -1;
    __syncthreads();
    for (int e = tid; e < EE; e += 1024) {
        int s = edge_index[e], d = edge_index[EE + e];
        atomicOr(&bm[s * 16 + (d >> 5)], 1u << (d & 31));
        atomicOr(&bm[d * 16 + (s >> 5)], 1u << (s & 31));
    }
    __syncthreads();
    if (tid < NN) {
        int cnt = 0;
        for (int w = 0; w < 16; ++w) {
            unsigned int bits = bm[tid * 16 + w];
            while (bits) {
                int b = __ffs(bits) - 1;
                bits &= bits - 1u;
                g_nbrs[tid][cnt++] = w * 32 + b;
            }
        }
        g_degs[tid] = cnt;
    }
    if (tid == 0) {
        int s0 = 0;
        for (int n = 0; n < NN; ++n) if (starts[n] != 0) s_nodes[s0++] = n;
        sh_misc[0] = s0;
    }
    __syncthreads();
    const int S0 = sh_misc[0];
    int known = (S0 < MAX_STEPS) ? S0 : MAX_STEPS;
    for (int i = tid; i < known; i += 1024) g_sched[i].x = s_nodes[i];
    for (int idx = tid; idx < known * MSGD; idx += 1024) {
        int i = idx >> 7, o = idx & (MSGD - 1);
        g_qmsgs[i][o] = first_message[s_nodes[i] * MSGD + o];
    }
    __syncthreads();

    // round-expansion of the queue schedule
    for (int round = 0; round < 8 && known > 0; ++round) {
        const int C = (known + 1023) >> 10;
        const int base = tid * C;
        int lsum = 0;
        for (int j = 0; j < C; ++j) {
            int i = base + j;
            if (i < known) lsum += g_degs[g_sched[i].x];
        }
        scanbuf[0][tid] = lsum;
        __syncthreads();
        int src = 0;
        for (int off = 1; off < 1024; off <<= 1) {
            int v = scanbuf[src][tid];
            if (tid >= off) v += scanbuf[src][tid - off];
            scanbuf[src ^ 1][tid] = v;
            src ^= 1;
            __syncthreads();
        }
        const int excl = (tid == 0) ? 0 : scanbuf[src][tid - 1];
        const int total = scanbuf[src][1023];
        int t = S0 + excl;
        for (int j = 0; j < C; ++j) {
            int i = base + j;
            if (i < known) {
                int nd = g_sched[i].x;
                int dg = g_degs[nd];
                g_sched[i].y = t;
                g_sched[i].z = dg;
                for (int e = 0; e < dg; ++e) {
                    int pos = t + e;
                    if (pos >= known && pos < MAX_STEPS) {
                        g_sched[pos].x = g_nbrs[nd][e];
                        g_prod[pos] = i;
                    }
                }
                t += dg;
            }
        }
        __syncthreads();
        int newknown = S0 + total;
        if (newknown > MAX_STEPS) newknown = MAX_STEPS;
        if (newknown == known) break;
        known = newknown;
    }
    __syncthreads();
    const int kn = known;
    if (tid == 0) sh_misc[1] = kn;
    __syncthreads();
    for (int i = tid; i < kn; i += 1024) {
        if (g_sched[i].y <= i) atomicMin(&sh_misc[1], i);   // first drained step
    }
    __syncthreads();
    const int istar = sh_misc[1];
    for (int i = tid; i < MAX_STEPS; i += 1024) {
        if (i >= kn) { g_sched[i].x = 0; g_sched[i].y = 0x7fffffff; g_sched[i].z = 0; }
    }
    __syncthreads();

    // ---- batch construction (sequential, message-independent) ----
    if (tid == 0) {
        int nb = 0;
        if (istar > 0) {
            unsigned long long seen[8] = {0, 0, 0, 0, 0, 0, 0, 0};
            int b = 0, bsz = 0;
            g_bstart[0] = 0;
            for (int i = 0; i < istar; ++i) {
                const int v = g_sched[i].x;
                const int p = g_prod[i];
                const bool nconf = (bsz >= BMAX) || ((seen[v >> 6] >> (v & 63)) & 1ull);
                const bool pconf = (p >= 0 && g_bid[p] >= b - 1);
                if (nconf || pconf) {
                    ++b; g_bstart[b] = i;
                    for (int k = 0; k < 8; ++k) seen[k] = 0;
                    bsz = 0;
                    if (p >= 0 && g_bid[p] >= b - 1) { ++b; g_bstart[b] = i; }  // empty batch
                }
                g_bid[i] = b;
                seen[v >> 6] |= 1ull << (v & 63);
                ++bsz;
            }
            nb = b + 1;
            g_bstart[nb] = istar;
        }
        g_nbatch = nb;
        g_bar_cnt = 0;
        g_bar_gen = 0;
    }
}

// ---------------- main persistent kernel: 8 groups x 16 slice-WGs ----------------
__global__ __launch_bounds__(TPB, 1) void k_main(const float* __restrict__ W_ih,
                                                 const float* __restrict__ W_hh,
                                                 const float* __restrict__ b_ih,
                                                 const float* __restrict__ b_hh,
                                                 const float* __restrict__ nm_W,
                                                 const float* __restrict__ nm_b,
                                                 const float* __restrict__ dec_W,
                                                 const float* __restrict__ dec_b,
                                                 float* __restrict__ out) {
    __shared__ float sWih[GROWS][136];   // stride%32==8 -> 2 lanes/bank (free)
    __shared__ float sWhh[GROWS][264];
    __shared__ float sNmH[MSGD][17];
    __shared__ float sNmM[MSGD][9];
    __shared__ float sBias[GROWS];
    __shared__ float sAct[MSGD + HID];
    __shared__ float sGates[GROWS];
    __shared__ float sHnew[UPW];

    const int tid = threadIdx.x;
    const int wg  = blockIdx.x;
    const int w   = wg & (NWG - 1);     // slice id within group
    const int grp = wg >> 4;            // group id 0..7

    // one-time weight slice load
    for (int idx = tid; idx < GROWS * MSGD; idx += TPB) {
        int r = idx >> 7, c = idx & (MSGD - 1);
        int G = (r / UPW) * HID + w * UPW + (r % UPW);
        sWih[r][c] = W_ih[G * MSGD + c];
    }
    for (int idx = tid; idx < GROWS * HID; idx += TPB) {
        int r = idx >> 8, c = idx & (HID - 1);
        int G = (r / UPW) * HID + w * UPW + (r % UPW);
        sWhh[r][c] = W_hh[G * HID + c];
    }
    if (tid < GROWS) {
        int G = (tid / UPW) * HID + w * UPW + (tid % UPW);
        sBias[tid] = b_ih[G] + b_hh[G];
    }
    for (int idx = tid; idx < MSGD * UPW; idx += TPB) {
        int o = idx / UPW, u = idx % UPW;
        sNmH[o][u] = nm_W[o * (HID + MSGD) + w * UPW + u];
    }
    for (int idx = tid; idx < MSGD * MPW; idx += TPB) {
        int o = idx / MPW, m = idx % MPW;
        sNmM[o][m] = nm_W[o * (HID + MSGD) + HID + w * MPW + m];
    }
    __syncthreads();

    const int nbatch = g_nbatch;

    for (int b = 0; b <= nbatch; ++b) {
        // ---- finalize previous batch's messages (all 128 WGs, strided) ----
        if (b > 0) {
            const int fs = g_bstart[b - 1], fe = g_bstart[b];
            for (int s = fs + wg; s < fe; s += NWGTOT) {
                const int4 sp = g_sched[s];
                const int tp = sp.y, dg = sp.z;
                if (tp < MAX_STEPS && tid < MSGD) {
                    float m = nm_b[tid];
#pragma unroll
                    for (int k = 0; k < NWG; ++k) m += g_partials[s & (PSLOTS - 1)][k][tid];
                    const int lim = (tp + dg <= MAX_STEPS) ? dg : (MAX_STEPS - tp);
                    for (int e = 0; e < lim; ++e) g_qmsgs[tp + e][tid] = m;
                }
            }
        }
        // ---- compute batch b (distinct nodes -> fully parallel) ----
        if (b < nbatch) {
            const int bs = g_bstart[b], be = g_bstart[b + 1];
            for (int i = bs + grp; i < be; i += NGROUP) {
                const int4 sc = g_sched[i];
                const int node = sc.x, tpos = sc.y;
                // stage [msg | h_prev]
                if (tid < MSGD + HID) {
                    sAct[tid] = (tid < MSGD) ? g_qmsgs[i][tid] : g_hid[node][tid - MSGD];
                }
                __syncthreads();
                // 64 gate rows x 384-dot, 8 lanes/row
                {
                    const int r = tid >> 3, sub = tid & 7;
                    float a0 = 0.0f, a1 = 0.0f;
#pragma unroll
                    for (int j = 0; j < 16; j += 2) {
                        a0 += sWih[r][sub + 8 * j]       * sAct[sub + 8 * j];
                        a1 += sWih[r][sub + 8 * (j + 1)] * sAct[sub + 8 * (j + 1)];
                    }
#pragma unroll
                    for (int j = 0; j < 32; j += 2) {
                        a0 += sWhh[r][sub + 8 * j]       * sAct[MSGD + sub + 8 * j];
                        a1 += sWhh[r][sub + 8 * (j + 1)] * sAct[MSGD + sub + 8 * (j + 1)];
                    }
                    float acc = a0 + a1;
                    acc += __shfl_xor(acc, 1);
                    acc += __shfl_xor(acc, 2);
                    acc += __shfl_xor(acc, 4);
                    if (sub == 0) sGates[r] = acc + sBias[r];
                }
                __syncthreads();
                // LSTM cell update, immediate apply (torch gate order i,f,g,o)
                if (tid < UPW) {
                    const int u = tid, gu = w * UPW + u;
                    const float gi = sGates[u];
                    const float gf = sGates[UPW + u];
                    const float gg = sGates[2 * UPW + u];
                    const float go = sGates[3 * UPW + u];
                    const float cp = g_cell[node][gu];
                    const float cn = sigm(gf) * cp + sigm(gi) * tanhf(gg);
                    const float hn = sigm(go) * tanhf(cn);
                    g_hid[node][gu]  = hn;
                    g_cell[node][gu] = cn;
                    sHnew[u] = hn;
                }
                __syncthreads();
                // nm partial for this slice
                if (tpos < MAX_STEPS && tid < MSGD) {
                    float a = 0.0f;
#pragma unroll
                    for (int u = 0; u < UPW; ++u) a += sNmH[tid][u] * sHnew[u];
#pragma unroll
                    for (int m = 0; m < MPW; ++m) a += sNmM[tid][m] * sAct[w * MPW + m];
                    g_partials[i & (PSLOTS - 1)][w][tid] = a;
                }
                __syncthreads();
            }
        }
        grid_barrier();
    }

    // ---- decoder: 2048 rows x 16 lanes over 65536 threads ----
    const int gtid = wg * TPB + tid;
    const int row = gtid >> 4, lane = gtid & 15;
    if (row < PPD * NN) {
        const int p = row >> 9, n = row & (NN - 1);
        const float* dw = dec_W + (p * OUTC + lane) * HID;
        float acc = dec_b[p * OUTC + lane];
#pragma unroll 4
        for (int h = 0; h < HID; ++h) acc += g_hid[n][h] * dw[h];
        float mx = acc;
        mx = fmaxf(mx, __shfl_xor(mx, 1));
        mx = fmaxf(mx, __shfl_xor(mx, 2));
        mx = fmaxf(mx, __shfl_xor(mx, 4));
        mx = fmaxf(mx, __shfl_xor(mx, 8));
        float s = expf(acc - mx);
        s += __shfl_xor(s, 1);
        s += __shfl_xor(s, 2);
        s += __shfl_xor(s, 4);
        s += __shfl_xor(s, 8);
        out[row * OUTC + lane] = acc - mx - logf(s);
    }
}

extern "C" void kernel_launch(void* const* d_in, const int* in_sizes, int n_in,
                              void* d_out, int out_size, void* d_ws, size_t ws_size,
                              hipStream_t stream) {
    (void)in_sizes; (void)n_in; (void)out_size; (void)d_ws; (void)ws_size;
    const float* xa   = (const float*)d_in[0];
    const float* fm   = (const float*)d_in[1];
    const int*   ei   = (const int*)d_in[2];
    const int*   st   = (const int*)d_in[3];
    const float* encW = (const float*)d_in[4];
    const float* encb = (const float*)d_in[5];
    const float* Wih  = (const float*)d_in[6];
    const float* Whh  = (const float*)d_in[7];
    const float* bih  = (const float*)d_in[8];
    const float* bhh  = (const float*)d_in[9];
    const float* nmW  = (const float*)d_in[10];
    const float* nmb  = (const float*)d_in[11];
    const float* decW = (const float*)d_in[12];
    const float* decb = (const float*)d_in[13];
    float* out = (float*)d_out;

    hipLaunchKernelGGL(k_encoder, dim3(512), dim3(256), 0, stream, xa, encW, encb);
    hipLaunchKernelGGL(k_graph,   dim3(1),   dim3(1024), 0, stream, ei, st, fm);
    hipLaunchKernelGGL(k_main,    dim3(NWGTOT), dim3(TPB), 0, stream,
                       Wih, Whh, bih, bhh, nmW, nmb, decW, decb, out);
}

// Round 3
// 3021.658 us; speedup vs baseline: 11.5337x; 3.9967x over previous
//
#include <hip/hip_runtime.h>
#include <math.h>

// ---------------- problem constants ----------------
#define NN 512
#define EE 2048
#define IN_F 64
#define HID 256
#define MSGD 128
#define OUTC 16
#define PPD 4
#define MAX_STEPS 5120

// ---------------- kernel config ----------------
#define G 128              // dataflow workgroups (static node->WG assignment)
#define TPBM 512           // threads per WG in k_main (2 gate rows/thread)
#define KB 4               // max parallel steps per sub-batch (distinct nodes)
#define KG 16              // max steps per fence-group (one acquire per group)

// ---------------- device globals (re-initialized every call) ----------------
__device__ int   g_nbrs[NN][NN];
__device__ int   g_degs[NN];
__device__ int4  g_sched[MAX_STEPS];   // x=node, y=t(enqueue base), z=deg, w=unused
__device__ int   g_prod[MAX_STEPS];    // producer step of queue position (-1 = initial)
__device__ int   g_mready[MAX_STEPS];  // message-ready flags
__device__ int   g_glist[G][MAX_STEPS];
__device__ int   g_gcnt[G];
__device__ float g_qmsgs[MAX_STEPS][MSGD];
__device__ float g_hid[NN][HID];
__device__ float g_cell[NN][HID];

__device__ __forceinline__ float sigm(float x) { return 1.0f / (1.0f + expf(-x)); }

// ---------------- kernel A: encoder hid = xa @ enc_W^T + enc_b ; cell = 0 ----------------
__global__ __launch_bounds__(256) void k_encoder(const float* __restrict__ xa,
                                                 const float* __restrict__ enc_W,
                                                 const float* __restrict__ enc_b) {
    int gid = blockIdx.x * 256 + threadIdx.x;
    int n = gid >> 8, c = gid & 255;
    const float* x = xa + n * IN_F;
    const float* w = enc_W + c * IN_F;
    float acc = enc_b[c];
#pragma unroll 8
    for (int j = 0; j < IN_F; ++j) acc += x[j] * w[j];
    g_hid[n][c] = acc;
    g_cell[n][c] = 0.0f;
}

// ---------------- kernel B: graph prep + schedule + group assignment ----------------
__global__ __launch_bounds__(1024) void k_graph(const int* __restrict__ edge_index,
                                                const int* __restrict__ starts,
                                                const float* __restrict__ first_message) {
    __shared__ unsigned int bm[NN * 16];     // adjacency bitmap; later reused as nodestep
    __shared__ int s_nodes[NN];
    __shared__ int scanbuf[2][1024];
    __shared__ int sh_misc[4];
    __shared__ int s_cnt[NN];
    __shared__ int s_grp[NN];
    const int tid = threadIdx.x;

    for (int i = tid; i < NN * 16; i += 1024) bm[i] = 0u;
    for (int i = tid; i < MAX_STEPS; i += 1024) g_prod[i] = -1;
    __syncthreads();
    for (int e = tid; e < EE; e += 1024) {
        int s = edge_index[e], d = edge_index[EE + e];
        atomicOr(&bm[s * 16 + (d >> 5)], 1u << (d & 31));
        atomicOr(&bm[d * 16 + (s >> 5)], 1u << (s & 31));
    }
    __syncthreads();
    if (tid < NN) {
        int cnt = 0;
        for (int w = 0; w < 16; ++w) {
            unsigned int bits = bm[tid * 16 + w];
            while (bits) {
                int b = __ffs(bits) - 1;
                bits &= bits - 1u;
                g_nbrs[tid][cnt++] = w * 32 + b;   // ascending => sorted set
            }
        }
        g_degs[tid] = cnt;
    }
    if (tid == 0) {
        int s0 = 0;
        for (int n = 0; n < NN; ++n) if (starts[n] != 0) s_nodes[s0++] = n;
        sh_misc[0] = s0;
    }
    __syncthreads();
    const int S0 = sh_misc[0];
    int known = (S0 < MAX_STEPS) ? S0 : MAX_STEPS;
    for (int i = tid; i < known; i += 1024) g_sched[i].x = s_nodes[i];
    for (int idx = tid; idx < known * MSGD; idx += 1024) {
        int i = idx >> 7, o = idx & (MSGD - 1);
        g_qmsgs[i][o] = first_message[s_nodes[i] * MSGD + o];
    }
    __syncthreads();

    // round-expansion of the queue schedule (message-independent)
    for (int round = 0; round < 8 && known > 0; ++round) {
        const int C = (known + 1023) >> 10;
        const int base = tid * C;
        int lsum = 0;
        for (int j = 0; j < C; ++j) {
            int i = base + j;
            if (i < known) lsum += g_degs[g_sched[i].x];
        }
        scanbuf[0][tid] = lsum;
        __syncthreads();
        int src = 0;
        for (int off = 1; off < 1024; off <<= 1) {
            int v = scanbuf[src][tid];
            if (tid >= off) v += scanbuf[src][tid - off];
            scanbuf[src ^ 1][tid] = v;
            src ^= 1;
            __syncthreads();
        }
        const int excl = (tid == 0) ? 0 : scanbuf[src][tid - 1];
        const int total = scanbuf[src][1023];
        int t = S0 + excl;
        for (int j = 0; j < C; ++j) {
            int i = base + j;
            if (i < known) {
                int nd = g_sched[i].x;
                int dg = g_degs[nd];
                g_sched[i].y = t;
                g_sched[i].z = dg;
                for (int e = 0; e < dg; ++e) {
                    int pos = t + e;
                    if (pos >= known && pos < MAX_STEPS) {
                        g_sched[pos].x = g_nbrs[nd][e];
                        g_prod[pos] = i;
                    }
                }
                t += dg;
            }
        }
        __syncthreads();
        int newknown = S0 + total;
        if (newknown > MAX_STEPS) newknown = MAX_STEPS;
        if (newknown == known) break;
        known = newknown;
    }
    __syncthreads();
    const int kn = known;
    if (tid == 0) sh_misc[1] = kn;
    __syncthreads();
    for (int i = tid; i < kn; i += 1024) {
        if (g_sched[i].y <= i) atomicMin(&sh_misc[1], i);   // first drained step
    }
    __syncthreads();
    const int istar = sh_misc[1];
    for (int i = tid; i < MAX_STEPS; i += 1024) {
        if (i >= kn) { g_sched[i].x = 0; g_sched[i].y = 0x7fffffff; g_sched[i].z = 0; }
    }
    __syncthreads();

    // ---- occurrence counts + balanced node->group assignment + per-group lists ----
    int* s_nodestep = (int*)bm;              // bm no longer needed (8192 ints >= 5120)
    for (int i = tid; i < istar; i += 1024) s_nodestep[i] = g_sched[i].x;
    if (tid < NN) s_cnt[tid] = 0;
    __syncthreads();
    for (int i = tid; i < istar; i += 1024) atomicAdd(&s_cnt[s_nodestep[i]], 1);
    __syncthreads();
    if (tid < 64) {
        // lane l tracks loads of groups 2l, 2l+1; greedy least-loaded via wave argmin
        int ld0 = 0, ld1 = 0;
        for (int v = 0; v < NN; ++v) {
            const int c = s_cnt[v];
            const int sub = (ld1 < ld0) ? 1 : 0;
            const int myload = sub ? ld1 : ld0;
            int key = myload * 256 + (tid * 2 + sub);
#pragma unroll
            for (int off = 32; off >= 1; off >>= 1) {
                int ok = __shfl_xor(key, off);
                key = (ok < key) ? ok : key;
            }
            const int gid = key & 255;          // winning group id (< G)
            if ((gid >> 1) == tid) { if (gid & 1) ld1 += c; else ld0 += c; }
            if (tid == 0) s_grp[v] = gid;
        }
    }
    __syncthreads();
    if (tid < G) {
        int c = 0;
        for (int i = 0; i < istar; ++i)
            if (s_grp[s_nodestep[i]] == tid) g_glist[tid][c++] = i;
        g_gcnt[tid] = c;
    }
    for (int i = tid; i < MAX_STEPS; i += 1024) g_mready[i] = (i < S0) ? 1 : 0;
}

// ---------------- main dataflow kernel: G WGs, no grid barriers ----------------
__global__ __launch_bounds__(TPBM, 1) void k_main(const float* __restrict__ W_ih,
                                                  const float* __restrict__ W_hh,
                                                  const float* __restrict__ b_ih,
                                                  const float* __restrict__ b_hh,
                                                  const float* __restrict__ nm_W,
                                                  const float* __restrict__ nm_b) {
    __shared__ float sAct[KB][384];        // [msg(128) | h_prev(256)] per sub-batch col
    __shared__ float sGates[KB][1024];     // gate exchange; reused as nm partials
    __shared__ float sH[KB][256];
    __shared__ int   sSteps[KG];
    __shared__ int   sNode[KG];
    __shared__ int   sSub[KG + 1];
    __shared__ int   sMeta[4];             // [0]=gsz [1]=nsub [2]=anyMsg
    float* sPart = &sGates[0][0];          // [KB][128][4] alias

    const int tid = threadIdx.x;
    const int wg  = blockIdx.x;
    const int cnt = g_gcnt[wg];

    const int r0 = tid, r1 = tid + 512;    // my two gate rows
    const float vb0 = b_ih[r0] + b_hh[r0];
    const float vb1 = b_ih[r1] + b_hh[r1];
    const float* wih0 = W_ih + r0 * MSGD;
    const float* wih1 = W_ih + r1 * MSGD;
    const float* whh0 = W_hh + r0 * HID;
    const float* whh1 = W_hh + r1 * HID;

    int pos = 0;
    while (pos < cnt) {
        // ---- build fence-group (thread 0): consecutive list steps, producers all
        // before group start (=> poll-then-compute is deadlock-free by induction) ----
        if (tid == 0) {
            const int first = g_glist[wg][pos];
            const int kg = (first < 1024) ? KB : KG;   // small groups during warmup
            int gsz = 0, anyMsg = 0;
            while (gsz < kg && pos + gsz < cnt) {
                const int s = g_glist[wg][pos + gsz];
                if (gsz > 0 && g_prod[s] >= first) break;
                sSteps[gsz] = s;
                sNode[gsz]  = g_sched[s].x;
                if (g_sched[s].y < MAX_STEPS) anyMsg = 1;
                ++gsz;
            }
            // sub-batches: maximal prefixes of distinct nodes, <= KB
            int nsub = 0, st = 0;
            sSub[0] = 0;
            while (st < gsz) {
                int e = st + 1;
                while (e < gsz && e - st < KB) {
                    bool dup = false;
                    for (int k = st; k < e; ++k)
                        if (sNode[k] == sNode[e]) { dup = true; break; }
                    if (dup) break;
                    ++e;
                }
                ++nsub; sSub[nsub] = e; st = e;
            }
            sMeta[0] = gsz; sMeta[1] = nsub; sMeta[2] = anyMsg;
        }
        __syncthreads();
        const int gsz = sMeta[0], nsub = sMeta[1], anyMsg = sMeta[2];

        // ---- poll all group messages once, then one acquire fence ----
        if (tid < gsz) {
            const int s = sSteps[tid];
            while (__hip_atomic_load(&g_mready[s], __ATOMIC_RELAXED,
                                     __HIP_MEMORY_SCOPE_AGENT) == 0)
                __builtin_amdgcn_s_sleep(1);
        }
        __syncthreads();
        __builtin_amdgcn_fence(__ATOMIC_ACQUIRE, "agent");

        for (int j = 0; j < nsub; ++j) {
            const int a = sSub[j], B = sSub[j + 1] - a;
            // stage [msg | h_prev]; zero-fill unused columns
            for (int idx = tid; idx < KB * 384; idx += TPBM) {
                const int k = idx / 384, c = idx - k * 384;
                float v = 0.0f;
                if (k < B) {
                    const int s = sSteps[a + k];
                    v = (c < MSGD) ? g_qmsgs[s][c] : g_hid[sNode[a + k]][c - MSGD];
                }
                sAct[k][c] = v;
            }
            __syncthreads();
            // gates: 2 rows/thread, KB columns, acts broadcast from LDS
            {
                float acc0[KB], acc1[KB];
#pragma unroll
                for (int k = 0; k < KB; ++k) { acc0[k] = vb0; acc1[k] = vb1; }
#pragma unroll 4
                for (int c = 0; c < MSGD; c += 4) {
                    const float4 w0 = *(const float4*)(wih0 + c);
                    const float4 w1 = *(const float4*)(wih1 + c);
#pragma unroll
                    for (int k = 0; k < KB; ++k) {
                        const float4 aa = *(const float4*)&sAct[k][c];
                        acc0[k] += w0.x * aa.x + w0.y * aa.y + w0.z * aa.z + w0.w * aa.w;
                        acc1[k] += w1.x * aa.x + w1.y * aa.y + w1.z * aa.z + w1.w * aa.w;
                    }
                }
#pragma unroll 4
                for (int c = 0; c < HID; c += 4) {
                    const float4 w0 = *(const float4*)(whh0 + c);
                    const float4 w1 = *(const float4*)(whh1 + c);
#pragma unroll
                    for (int k = 0; k < KB; ++k) {
                        const float4 aa = *(const float4*)&sAct[k][MSGD + c];
                        acc0[k] += w0.x * aa.x + w0.y * aa.y + w0.z * aa.z + w0.w * aa.w;
                        acc1[k] += w1.x * aa.x + w1.y * aa.y + w1.z * aa.z + w1.w * aa.w;
                    }
                }
#pragma unroll
                for (int k = 0; k < KB; ++k) {
                    sGates[k][r0] = acc0[k];
                    sGates[k][r1] = acc1[k];
                }
            }
            __syncthreads();
            // LSTM cell update (torch gate order i,f,g,o); immediate apply (node-local)
            for (int idx = tid; idx < B * HID; idx += TPBM) {
                const int k = idx >> 8, u = idx & (HID - 1);
                const int node = sNode[a + k];
                const float gi = sGates[k][u],       gf = sGates[k][256 + u];
                const float gg = sGates[k][512 + u], go = sGates[k][768 + u];
                const float cp = g_cell[node][u];
                const float cn = sigm(gf) * cp + sigm(gi) * tanhf(gg);
                const float hn = sigm(go) * tanhf(cn);
                g_cell[node][u] = cn;
                g_hid[node][u]  = hn;
                sH[k][u] = hn;
            }
            __syncthreads();   // gates consumed; sPart alias now safe
            // nm partials: ro = tid>>2 (0..127), sl = tid&3, cols [sl*96, sl*96+96)
            {
                const int ro = tid >> 2, sl = tid & 3;
                const float* wrow = nm_W + ro * 384 + sl * 96;
                float p[KB];
#pragma unroll
                for (int k = 0; k < KB; ++k) p[k] = 0.0f;
#pragma unroll 4
                for (int c = 0; c < 96; c += 4) {
                    const float4 w = *(const float4*)(wrow + c);
                    const int col = sl * 96 + c;
#pragma unroll
                    for (int k = 0; k < KB; ++k) {
                        float4 aa;
                        if (col < HID) aa = *(const float4*)&sH[k][col];
                        else           aa = *(const float4*)&sAct[k][col - HID];
                        p[k] += w.x * aa.x + w.y * aa.y + w.z * aa.z + w.w * aa.w;
                    }
                }
#pragma unroll
                for (int k = 0; k < KB; ++k) sPart[((k * 128) + ro) * 4 + sl] = p[k];
            }
            __syncthreads();
            // reduce + write outgoing messages (deg copies at queue tail)
            for (int idx = tid; idx < B * MSGD; idx += TPBM) {
                const int k = idx >> 7, o = idx & (MSGD - 1);
                const int s = sSteps[a + k];
                const int4 sc = g_sched[s];
                if (sc.y < MAX_STEPS) {
                    const float* pp = &sPart[((k * 128) + o) * 4];
                    const float m = nm_b[o] + pp[0] + pp[1] + pp[2] + pp[3];
                    const int lim = (sc.y + sc.z <= MAX_STEPS) ? sc.z : (MAX_STEPS - sc.y);
                    for (int e = 0; e < lim; ++e) g_qmsgs[sc.y + e][o] = m;
                }
            }
            __syncthreads();
        }
        // ---- group end: publish flags (one release fence for all writes) ----
        if (anyMsg) {
            __builtin_amdgcn_fence(__ATOMIC_RELEASE, "agent");
            if (tid < gsz) {
                const int s = sSteps[tid];
                const int4 sc = g_sched[s];
                if (sc.y < MAX_STEPS) {
                    const int lim = (sc.y + sc.z <= MAX_STEPS) ? sc.z : (MAX_STEPS - sc.y);
                    for (int e = 0; e < lim; ++e)
                        __hip_atomic_store(&g_mready[sc.y + e], 1, __ATOMIC_RELAXED,
                                           __HIP_MEMORY_SCOPE_AGENT);
                }
            }
        }
        pos += gsz;
        __syncthreads();
    }
}

// ---------------- decoder: logits + log_softmax ----------------
__global__ __launch_bounds__(256) void k_decode(const float* __restrict__ dec_W,
                                                const float* __restrict__ dec_b,
                                                float* __restrict__ out) {
    const int gtid = blockIdx.x * 256 + threadIdx.x;
    const int row = gtid >> 4, lane = gtid & 15;   // row = p*NN + n
    const int p = row >> 9, n = row & (NN - 1);
    const float* dw = dec_W + (p * OUTC + lane) * HID;
    float acc = dec_b[p * OUTC + lane];
#pragma unroll 8
    for (int j = 0; j < HID; j += 4) {
        const float4 hv = *(const float4*)&g_hid[n][j];
        const float4 wv = *(const float4*)(dw + j);
        acc += hv.x * wv.x + hv.y * wv.y + hv.z * wv.z + hv.w * wv.w;
    }
    float mx = acc;
    mx = fmaxf(mx, __shfl_xor(mx, 1));
    mx = fmaxf(mx, __shfl_xor(mx, 2));
    mx = fmaxf(mx, __shfl_xor(mx, 4));
    mx = fmaxf(mx, __shfl_xor(mx, 8));
    float s = expf(acc - mx);
    s += __shfl_xor(s, 1);
    s += __shfl_xor(s, 2);
    s += __shfl_xor(s, 4);
    s += __shfl_xor(s, 8);
    out[row * OUTC + lane] = acc - mx - logf(s);
}

extern "C" void kernel_launch(void* const* d_in, const int* in_sizes, int n_in,
                              void* d_out, int out_size, void* d_ws, size_t ws_size,
                              hipStream_t stream) {
    (void)in_sizes; (void)n_in; (void)out_size; (void)d_ws; (void)ws_size;
    const float* xa   = (const float*)d_in[0];
    const float* fm   = (const float*)d_in[1];
    const int*   ei   = (const int*)d_in[2];
    const int*   st   = (const int*)d_in[3];
    const float* encW = (const float*)d_in[4];
    const float* encb = (const float*)d_in[5];
    const float* Wih  = (const float*)d_in[6];
    const float* Whh  = (const float*)d_in[7];
    const float* bih  = (const float*)d_in[8];
    const float* bhh  = (const float*)d_in[9];
    const float* nmW  = (const float*)d_in[10];
    const float* nmb  = (const float*)d_in[11];
    const float* decW = (const float*)d_in[12];
    const float* decb = (const float*)d_in[13];
    float* out = (float*)d_out;

    hipLaunchKernelGGL(k_encoder, dim3(512), dim3(256), 0, stream, xa, encW, encb);
    hipLaunchKernelGGL(k_graph,   dim3(1),   dim3(1024), 0, stream, ei, st, fm);
    hipLaunchKernelGGL(k_main,    dim3(G),   dim3(TPBM), 0, stream,
                       Wih, Whh, bih, bhh, nmW, nmb);
    hipLaunchKernelGGL(k_decode,  dim3(128), dim3(256), 0, stream, decW, decb, out);
}

// Round 4
// 1765.088 us; speedup vs baseline: 19.7446x; 1.7119x over previous
//
#include <hip/hip_runtime.h>
#include <math.h>

// ---------------- problem constants ----------------
#define NN 512
#define EE 2048
#define IN_F 64
#define HID 256
#define MSGD 128
#define OUTC 16
#define MAX_STEPS 5120

// ---------------- kernel config ----------------
#define NWGA 256      // phase-A WGs (node & 255 ownership)
#define NWGB 128      // phase-B WGs
#define KB 4          // phase-B lockstep node-chain slots per WG

// ---------------- device globals (all rewritten every call) ----------------
__device__ int   g_nbrs[NN][NN];
__device__ int   g_degs[NN];
__device__ int4  g_sched[MAX_STEPS];     // x=node, y=t(enqueue base), z=deg
__device__ int   g_mready[MAX_STEPS];
__device__ int   g_S0, g_T;              // T = istar (number of active steps)
__device__ int   g_alist[NWGA][MAX_STEPS];
__device__ int   g_acnt[NWGA];
__device__ int   g_noff[NN + 1];
__device__ int   g_nlist[MAX_STEPS];     // phase-B steps grouped by node
__device__ int   g_bq[NWGB][NN];
__device__ int   g_bqcnt[NWGB];
__device__ float g_qmsgs[MAX_STEPS][MSGD];
__device__ float g_hid[NN][HID];
__device__ float g_cell[NN][HID];
__device__ float g_WT[384 * 1024];       // transposed gate weights [c][r]
__device__ float g_nmT[384 * MSGD];      // transposed nm weights [c][o]
__device__ float g_bias[1024];           // b_ih + b_hh

__device__ __forceinline__ float sigm(float x) { return 1.0f / (1.0f + expf(-x)); }

// ---------------- encoder: hid = xa @ enc_W^T + enc_b ; cell = 0 ----------------
__global__ __launch_bounds__(256) void k_encoder(const float* __restrict__ xa,
                                                 const float* __restrict__ enc_W,
                                                 const float* __restrict__ enc_b) {
    int gid = blockIdx.x * 256 + threadIdx.x;
    int n = gid >> 8, c = gid & 255;
    const float* x = xa + n * IN_F;
    const float* w = enc_W + c * IN_F;
    float acc = enc_b[c];
#pragma unroll 8
    for (int j = 0; j < IN_F; ++j) acc += x[j] * w[j];
    g_hid[n][c] = acc;
    g_cell[n][c] = 0.0f;
}

// ---------------- prep: transpose weights for coalesced streaming ----------------
__global__ __launch_bounds__(256) void k_prep(const float* __restrict__ W_ih,
                                              const float* __restrict__ W_hh,
                                              const float* __restrict__ b_ih,
                                              const float* __restrict__ b_hh,
                                              const float* __restrict__ nm_W) {
    const int c = blockIdx.x;         // 0..383
    const int t = threadIdx.x;
    for (int r = t; r < 1024; r += 256)
        g_WT[c * 1024 + r] = (c < MSGD) ? W_ih[r * MSGD + c] : W_hh[r * HID + (c - MSGD)];
    if (t < MSGD) g_nmT[c * MSGD + t] = nm_W[t * 384 + c];
    if (c == 0)
        for (int r = t; r < 1024; r += 256) g_bias[r] = b_ih[r] + b_hh[r];
}

// ---------------- graph prep + schedule + phase lists ----------------
__global__ __launch_bounds__(1024) void k_graph(const int* __restrict__ edge_index,
                                                const int* __restrict__ starts,
                                                const float* __restrict__ first_message) {
    __shared__ unsigned int bm[NN * 16];
    __shared__ int s_nodes[NN];
    __shared__ int scanbuf[2][1024];
    __shared__ int sh_misc[4];
    __shared__ int s_cnt[NN];
    __shared__ int s_grp[NN];
    const int tid = threadIdx.x;

    for (int i = tid; i < NN * 16; i += 1024) bm[i] = 0u;
    __syncthreads();
    for (int e = tid; e < EE; e += 1024) {
        int s = edge_index[e], d = edge_index[EE + e];
        atomicOr(&bm[s * 16 + (d >> 5)], 1u << (d & 31));
        atomicOr(&bm[d * 16 + (s >> 5)], 1u << (s & 31));
    }
    __syncthreads();
    if (tid < NN) {
        int cnt = 0;
        for (int w = 0; w < 16; ++w) {
            unsigned int bits = bm[tid * 16 + w];
            while (bits) {
                int b = __ffs(bits) - 1;
                bits &= bits - 1u;
                g_nbrs[tid][cnt++] = w * 32 + b;   // ascending => sorted neighbor set
            }
        }
        g_degs[tid] = cnt;
    }
    if (tid == 0) {
        int s0 = 0;
        for (int n = 0; n < NN; ++n) if (starts[n] != 0) s_nodes[s0++] = n;
        sh_misc[0] = s0;
    }
    __syncthreads();
    const int S0 = sh_misc[0];
    int known = (S0 < MAX_STEPS) ? S0 : MAX_STEPS;
    for (int i = tid; i < known; i += 1024) g_sched[i].x = s_nodes[i];
    for (int idx = tid; idx < known * MSGD; idx += 1024) {
        int i = idx >> 7, o = idx & (MSGD - 1);
        g_qmsgs[i][o] = first_message[s_nodes[i] * MSGD + o];
    }
    __syncthreads();

    // round-expansion of the queue schedule (message-independent)
    for (int round = 0; round < 8 && known > 0; ++round) {
        const int C = (known + 1023) >> 10;
        const int base = tid * C;
        int lsum = 0;
        for (int j = 0; j < C; ++j) {
            int i = base + j;
            if (i < known) lsum += g_degs[g_sched[i].x];
        }
        scanbuf[0][tid] = lsum;
        __syncthreads();
        int src = 0;
        for (int off = 1; off < 1024; off <<= 1) {
            int v = scanbuf[src][tid];
            if (tid >= off) v += scanbuf[src][tid - off];
            scanbuf[src ^ 1][tid] = v;
            src ^= 1;
            __syncthreads();
        }
        const int excl = (tid == 0) ? 0 : scanbuf[src][tid - 1];
        const int total = scanbuf[src][1023];
        int t = S0 + excl;
        for (int j = 0; j < C; ++j) {
            int i = base + j;
            if (i < known) {
                int nd = g_sched[i].x;
                int dg = g_degs[nd];
                g_sched[i].y = t;
                g_sched[i].z = dg;
                for (int e = 0; e < dg; ++e) {
                    int pos = t + e;
                    if (pos >= known && pos < MAX_STEPS) g_sched[pos].x = g_nbrs[nd][e];
                }
                t += dg;
            }
        }
        __syncthreads();
        int newknown = S0 + total;
        if (newknown > MAX_STEPS) newknown = MAX_STEPS;
        if (newknown == known) break;
        known = newknown;
    }
    __syncthreads();
    const int kn = known;
    if (tid == 0) { sh_misc[1] = kn; }
    __syncthreads();
    for (int i = tid; i < kn; i += 1024) {
        if (g_sched[i].y <= i) atomicMin(&sh_misc[1], i);   // first drained step
    }
    __syncthreads();
    const int istar = sh_misc[1];
    for (int i = tid; i < MAX_STEPS; i += 1024) {
        if (i >= kn) { g_sched[i].x = 0; g_sched[i].y = 0x7fffffff; g_sched[i].z = 0; }
    }
    if (tid == 0) sh_misc[2] = istar;
    __syncthreads();
    // P = first step whose enqueue base >= istar (everything later produces nothing consumed)
    for (int i = tid; i < istar; i += 1024)
        if (g_sched[i].y >= istar) atomicMin(&sh_misc[2], i);
    __syncthreads();
    const int P = sh_misc[2];
    if (tid == 0) { g_S0 = S0; g_T = istar; }

    // phase-A per-WG lists (node & 255 ownership, ascending step order)
    if (tid < NWGA) {
        int c = 0;
        for (int i = 0; i < P; ++i)
            if ((g_sched[i].x & (NWGA - 1)) == tid) g_alist[tid][c++] = i;
        g_acnt[tid] = c;
    }
    // phase-B per-node counts
    if (tid < NN) s_cnt[tid] = 0;
    __syncthreads();
    for (int i = P + tid; i < istar; i += 1024) atomicAdd(&s_cnt[g_sched[i].x], 1);
    __syncthreads();
    if (tid == 0) {
        int off = 0;
        for (int v = 0; v < NN; ++v) { g_noff[v] = off; off += s_cnt[v]; }
        g_noff[NN] = off;
    }
    __syncthreads();
    if (tid < NN) {
        int v = tid, c = g_noff[v];
        for (int i = P; i < istar; ++i)
            if (g_sched[i].x == v) g_nlist[c++] = i;
    }
    __syncthreads();
    // greedy least-loaded node -> phase-B WG assignment (64-lane wave argmin)
    if (tid < 64) {
        int ld0 = 0, ld1 = 0;
        for (int v = 0; v < NN; ++v) {
            const int c = s_cnt[v];
            const int sub = (ld1 < ld0) ? 1 : 0;
            const int myload = sub ? ld1 : ld0;
            int key = myload * 256 + (tid * 2 + sub);
#pragma unroll
            for (int off = 32; off >= 1; off >>= 1) {
                int ok = __shfl_xor(key, off);
                key = (ok < key) ? ok : key;
            }
            const int gid = key & 255;
            if ((gid >> 1) == tid) { if (gid & 1) ld1 += c; else ld0 += c; }
            if (tid == 0) s_grp[v] = gid;
        }
    }
    __syncthreads();
    if (tid < NWGB) {
        int c = 0;
        for (int v = 0; v < NN; ++v)
            if (s_grp[v] == tid && s_cnt[v] > 0) g_bq[tid][c++] = v;
        g_bqcnt[tid] = c;
    }
    for (int i = tid; i < MAX_STEPS; i += 1024) g_mready[i] = (i < S0) ? 1 : 0;
}

// ---------------- phase A: fence-free dataflow over steps [0, P) ----------------
__global__ __launch_bounds__(512, 1) void k_phaseA(const float* __restrict__ nm_b) {
    __shared__ float sAct[MSGD];
    __shared__ float sNH[2][HID], sNC[2][HID];
    __shared__ float sGates[1024];
    __shared__ float sPart[4 * MSGD];
    const int tid = threadIdx.x, wg = blockIdx.x;
    const int cntA = g_acnt[wg];
    if (cntA == 0) return;
    const int S0 = g_S0, T = g_T;
    const float vb0 = g_bias[2 * tid], vb1 = g_bias[2 * tid + 1];
    const float2* WT2 = (const float2*)g_WT;

    // my two candidate nodes: wg and wg+256
    for (int idx = tid; idx < 2 * HID; idx += 512) {
        int sl = idx >> 8, u = idx & 255, v = wg + (sl << 8);
        sNH[sl][u] = g_hid[v][u];
        sNC[sl][u] = g_cell[v][u];
    }
    __syncthreads();

    for (int k = 0; k < cntA; ++k) {
        const int s = g_alist[wg][k];
        const int4 sc = g_sched[s];
        const int node = sc.x, y = sc.y, deg = sc.z, sl = node >> 8;
        if (s >= S0) {
            if (tid == 0) {
                while (__hip_atomic_load(&g_mready[s], __ATOMIC_RELAXED,
                                         __HIP_MEMORY_SCOPE_AGENT) == 0)
                    __builtin_amdgcn_s_sleep(2);
            }
            __syncthreads();
            __builtin_amdgcn_fence(__ATOMIC_ACQUIRE, "workgroup");  // compiler/wave order only
        }
        // stage message (coherent scalar loads bypass stale L1/L2; no cache inv needed)
        if (tid < MSGD) {
            sAct[tid] = (s < S0) ? g_qmsgs[s][tid]
                                 : __hip_atomic_load(&g_qmsgs[s][tid], __ATOMIC_RELAXED,
                                                     __HIP_MEMORY_SCOPE_AGENT);
        }
        __syncthreads();
        // gates: rows 2t, 2t+1 via transposed weights (coalesced float2 per lane)
        {
            float acc0 = vb0, acc1 = vb1;
#pragma unroll 8
            for (int c = 0; c < MSGD; ++c) {
                const float2 w = WT2[c * 512 + tid];
                const float a = sAct[c];
                acc0 += w.x * a; acc1 += w.y * a;
            }
#pragma unroll 8
            for (int c = 0; c < HID; ++c) {
                const float2 w = WT2[(MSGD + c) * 512 + tid];
                const float h = sNH[sl][c];
                acc0 += w.x * h; acc1 += w.y * h;
            }
            ((float2*)sGates)[tid] = make_float2(acc0, acc1);
        }
        __syncthreads();
        // LSTM cell (torch order i,f,g,o)
        if (tid < HID) {
            const int u = tid;
            const float gi = sGates[u], gf = sGates[256 + u];
            const float gg = sGates[512 + u], go = sGates[768 + u];
            const float cp = sNC[sl][u];
            const float cn = sigm(gf) * cp + sigm(gi) * tanhf(gg);
            const float hn = sigm(go) * tanhf(cn);
            sNC[sl][u] = cn;
            sNH[sl][u] = hn;
        }
        __syncthreads();
        // nm partials: output o = tid&127, column-quarter cq = tid>>7
        {
            const int o = tid & (MSGD - 1), cq = tid >> 7;
            float p = 0.0f;
#pragma unroll 8
            for (int j = 0; j < 96; ++j) {
                const int c = cq + 4 * j;
                const float a = (c < HID) ? sNH[sl][c] : sAct[c - HID];
                p += g_nmT[c * MSGD + o] * a;
            }
            sPart[cq * MSGD + o] = p;
        }
        __syncthreads();
        const int lim = (y + deg <= T) ? deg : (T - y);
        if (tid < MSGD) {
            const float m = nm_b[tid] + sPart[tid] + sPart[MSGD + tid]
                          + sPart[2 * MSGD + tid] + sPart[3 * MSGD + tid];
            for (int e = 0; e < lim; ++e)
                __hip_atomic_store(&g_qmsgs[y + e][tid], m, __ATOMIC_RELAXED,
                                   __HIP_MEMORY_SCOPE_AGENT);
        }
        __syncthreads();   // drains every wave's vmcnt before flags
        if (tid < lim)
            __hip_atomic_store(&g_mready[y + tid], 1, __ATOMIC_RELAXED,
                               __HIP_MEMORY_SCOPE_AGENT);
    }
    __syncthreads();
    for (int idx = tid; idx < 2 * HID; idx += 512) {
        int sl = idx >> 8, u = idx & 255, v = wg + (sl << 8);
        g_hid[v][u]  = sNH[sl][u];
        g_cell[v][u] = sNC[sl][u];
    }
}

// ---------------- phase B: independent per-node chains, KB slots in lockstep ----------------
__global__ __launch_bounds__(512, 1) void k_phaseB() {
    __shared__ float sAct[KB][MSGD];
    __shared__ float sH[KB][HID], sC[KB][HID];
    __shared__ float sGates[KB][1024];
    __shared__ int sNode[KB], sPos[KB], sEnd[KB], sStep[KB], sFill[KB], sDrain[KB];
    __shared__ int sMeta[2];   // [0]=anyActive, [1]=queue pos
    const int tid = threadIdx.x, wg = blockIdx.x;
    const int qcnt = g_bqcnt[wg];
    const float vb0 = g_bias[2 * tid], vb1 = g_bias[2 * tid + 1];
    const float2* WT2 = (const float2*)g_WT;

    if (tid == 0) {
        int qp = 0;
        for (int k = 0; k < KB; ++k) {
            if (qp < qcnt) {
                int v = g_bq[wg][qp++];
                sNode[k] = v; sPos[k] = g_noff[v]; sEnd[k] = g_noff[v + 1]; sFill[k] = v;
            } else { sNode[k] = -1; sFill[k] = -1; }
            sDrain[k] = -1;
        }
        sMeta[1] = qp;
    }
    __syncthreads();
    for (int idx = tid; idx < KB * HID; idx += 512) {
        int k = idx >> 8, u = idx & 255, v = sFill[k];
        if (v >= 0) { sH[k][u] = g_hid[v][u]; sC[k][u] = g_cell[v][u]; }
    }
    __syncthreads();

    while (true) {
        if (tid == 0) {
            int any = 0;
            for (int k = 0; k < KB; ++k) {
                if (sNode[k] >= 0) { sStep[k] = g_nlist[sPos[k]]; any = 1; }
                else sStep[k] = -1;
            }
            sMeta[0] = any;
        }
        __syncthreads();
        if (!sMeta[0]) break;
        // stage messages (plain float4 — written in phase A, visible cross-kernel)
        for (int idx = tid; idx < KB * (MSGD / 4); idx += 512) {
            int k = idx >> 5, c4 = idx & 31, s = sStep[k];
            if (s >= 0) ((float4*)sAct[k])[c4] = ((const float4*)g_qmsgs[s])[c4];
        }
        __syncthreads();
        // gates: rows 2t,2t+1 x KB columns, coalesced transposed weights
        {
            float acc0[KB], acc1[KB];
#pragma unroll
            for (int k = 0; k < KB; ++k) { acc0[k] = vb0; acc1[k] = vb1; }
#pragma unroll 4
            for (int c = 0; c < MSGD; ++c) {
                const float2 w = WT2[c * 512 + tid];
#pragma unroll
                for (int k = 0; k < KB; ++k) {
                    const float a = sAct[k][c];
                    acc0[k] += w.x * a; acc1[k] += w.y * a;
                }
            }
#pragma unroll 4
            for (int c = 0; c < HID; ++c) {
                const float2 w = WT2[(MSGD + c) * 512 + tid];
#pragma unroll
                for (int k = 0; k < KB; ++k) {
                    const float h = sH[k][c];
                    acc0[k] += w.x * h; acc1[k] += w.y * h;
                }
            }
#pragma unroll
            for (int k = 0; k < KB; ++k)
                ((float2*)sGates[k])[tid] = make_float2(acc0[k], acc1[k]);
        }
        __syncthreads();
        // cell update in LDS
        for (int idx = tid; idx < KB * HID; idx += 512) {
            int k = idx >> 8, u = idx & 255;
            if (sStep[k] >= 0) {
                const float gi = sGates[k][u], gf = sGates[k][256 + u];
                const float gg = sGates[k][512 + u], go = sGates[k][768 + u];
                const float cp = sC[k][u];
                const float cn = sigm(gf) * cp + sigm(gi) * tanhf(gg);
                const float hn = sigm(go) * tanhf(cn);
                sC[k][u] = cn;
                sH[k][u] = hn;
            }
        }
        if (tid == 0) {
            int qp = sMeta[1];
            for (int k = 0; k < KB; ++k) {
                sDrain[k] = -1; sFill[k] = -1;
                if (sStep[k] >= 0 && ++sPos[k] == sEnd[k]) {
                    sDrain[k] = sNode[k];
                    if (qp < qcnt) {
                        int v = g_bq[wg][qp++];
                        sNode[k] = v; sPos[k] = g_noff[v]; sEnd[k] = g_noff[v + 1]; sFill[k] = v;
                    } else sNode[k] = -1;
                }
            }
            sMeta[1] = qp;
        }
        __syncthreads();
        for (int idx = tid; idx < KB * HID; idx += 512) {
            int k = idx >> 8, u = idx & 255, v = sDrain[k];
            if (v >= 0) g_hid[v][u] = sH[k][u];
        }
        __syncthreads();
        for (int idx = tid; idx < KB * HID; idx += 512) {
            int k = idx >> 8, u = idx & 255, v = sFill[k];
            if (v >= 0) { sH[k][u] = g_hid[v][u]; sC[k][u] = g_cell[v][u]; }
        }
        __syncthreads();
    }
}

// ---------------- decoder: logits + log_softmax ----------------
__global__ __launch_bounds__(256) void k_decode(const float* __restrict__ dec_W,
                                                const float* __restrict__ dec_b,
                                                float* __restrict__ out) {
    const int gtid = blockIdx.x * 256 + threadIdx.x;
    const int row = gtid >> 4, lane = gtid & 15;   // row = p*NN + n
    const int p = row >> 9, n = row & (NN - 1);
    const float* dw = dec_W + (p * OUTC + lane) * HID;
    float acc = dec_b[p * OUTC + lane];
#pragma unroll 8
    for (int j = 0; j < HID; j += 4) {
        const float4 hv = *(const float4*)&g_hid[n][j];
        const float4 wv = *(const float4*)(dw + j);
        acc += hv.x * wv.x + hv.y * wv.y + hv.z * wv.z + hv.w * wv.w;
    }
    float mx = acc;
    mx = fmaxf(mx, __shfl_xor(mx, 1));
    mx = fmaxf(mx, __shfl_xor(mx, 2));
    mx = fmaxf(mx, __shfl_xor(mx, 4));
    mx = fmaxf(mx, __shfl_xor(mx, 8));
    float s = expf(acc - mx);
    s += __shfl_xor(s, 1);
    s += __shfl_xor(s, 2);
    s += __shfl_xor(s, 4);
    s += __shfl_xor(s, 8);
    out[row * OUTC + lane] = acc - mx - logf(s);
}

extern "C" void kernel_launch(void* const* d_in, const int* in_sizes, int n_in,
                              void* d_out, int out_size, void* d_ws, size_t ws_size,
                              hipStream_t stream) {
    (void)in_sizes; (void)n_in; (void)out_size; (void)d_ws; (void)ws_size;
    const float* xa   = (const float*)d_in[0];
    const float* fm   = (const float*)d_in[1];
    const int*   ei   = (const int*)d_in[2];
    const int*   st   = (const int*)d_in[3];
    const float* encW = (const float*)d_in[4];
    const float* encb = (const float*)d_in[5];
    const float* Wih  = (const float*)d_in[6];
    const float* Whh  = (const float*)d_in[7];
    const float* bih  = (const float*)d_in[8];
    const float* bhh  = (const float*)d_in[9];
    const float* nmW  = (const float*)d_in[10];
    const float* nmb  = (const float*)d_in[11];
    const float* decW = (const float*)d_in[12];
    const float* decb = (const float*)d_in[13];
    float* out = (float*)d_out;

    hipLaunchKernelGGL(k_encoder, dim3(512),  dim3(256),  0, stream, xa, encW, encb);
    hipLaunchKernelGGL(k_prep,    dim3(384),  dim3(256),  0, stream, Wih, Whh, bih, bhh, nmW);
    hipLaunchKernelGGL(k_graph,   dim3(1),    dim3(1024), 0, stream, ei, st, fm);
    hipLaunchKernelGGL(k_phaseA,  dim3(NWGA), dim3(512),  0, stream, nmb);
    hipLaunchKernelGGL(k_phaseB,  dim3(NWGB), dim3(512),  0, stream);
    hipLaunchKernelGGL(k_decode,  dim3(128),  dim3(256),  0, stream, decW, decb, out);
}

// Round 5
// 1534.988 us; speedup vs baseline: 22.7043x; 1.1499x over previous
//
#include <hip/hip_runtime.h>
#include <math.h>

// ---------------- problem constants ----------------
#define NN 512
#define EE 2048
#define IN_F 64
#define HID 256
#define MSGD 128
#define OUTC 16
#define MAX_STEPS 5120

// ---------------- kernel config ----------------
#define NWGA 256      // phase-A WGs (node & 255 ownership)
#define NWGB 128      // phase-B WGs
#define KB 4          // phase-B lockstep node-chain slots per WG
#define MAXD 64       // padded neighbor-row stride (real max deg ~25)

// ---------------- device globals (all rewritten every call) ----------------
__device__ int   g_nbrs64[NN][MAXD];
__device__ int   g_degs[NN];
__device__ int4  g_sched[MAX_STEPS];     // x=node, y=t(enqueue base), z=deg
__device__ int   g_mready[MAX_STEPS];
__device__ int   g_S0, g_T;              // T = istar (number of active steps)
__device__ int   g_alist[NWGA][MAX_STEPS];
__device__ int   g_acnt[NWGA];
__device__ int   g_noff[NN + 1];
__device__ int   g_nlist[MAX_STEPS];     // phase-B steps grouped by node
__device__ int   g_bq[NWGB][NN];
__device__ int   g_bqcnt[NWGB];
__device__ float g_qmsgs[MAX_STEPS][MSGD];
__device__ float g_hid[NN][HID];
__device__ float g_cell[NN][HID];
__device__ float g_WT[384 * 1024];       // transposed gate weights [c][r]
__device__ float g_nmT[384 * MSGD];      // transposed nm weights [c][o]
__device__ float g_bias[1024];           // b_ih + b_hh

__device__ __forceinline__ float sigm(float x) { return 1.0f / (1.0f + expf(-x)); }

// ---------------- encoder: hid = xa @ enc_W^T + enc_b ; cell = 0 ----------------
__global__ __launch_bounds__(256) void k_encoder(const float* __restrict__ xa,
                                                 const float* __restrict__ enc_W,
                                                 const float* __restrict__ enc_b) {
    int gid = blockIdx.x * 256 + threadIdx.x;
    int n = gid >> 8, c = gid & 255;
    const float* x = xa + n * IN_F;
    const float* w = enc_W + c * IN_F;
    float acc = enc_b[c];
#pragma unroll 8
    for (int j = 0; j < IN_F; ++j) acc += x[j] * w[j];
    g_hid[n][c] = acc;
    g_cell[n][c] = 0.0f;
}

// ---------------- prep: transpose weights for coalesced streaming ----------------
__global__ __launch_bounds__(256) void k_prep(const float* __restrict__ W_ih,
                                              const float* __restrict__ W_hh,
                                              const float* __restrict__ b_ih,
                                              const float* __restrict__ b_hh,
                                              const float* __restrict__ nm_W) {
    const int c = blockIdx.x;         // 0..383
    const int t = threadIdx.x;
    for (int r = t; r < 1024; r += 256)
        g_WT[c * 1024 + r] = (c < MSGD) ? W_ih[r * MSGD + c] : W_hh[r * HID + (c - MSGD)];
    if (t < MSGD) g_nmT[c * MSGD + t] = nm_W[t * 384 + c];
    if (c == 0)
        for (int r = t; r < 1024; r += 256) g_bias[r] = b_ih[r] + b_hh[r];
}

// ---------------- neighbor lists: one block per node (parallel) ----------------
__global__ __launch_bounds__(256) void k_nbr(const int* __restrict__ edge_index) {
    __shared__ unsigned int bits[16];
    const int v = blockIdx.x, tid = threadIdx.x;
    if (tid < 16) bits[tid] = 0u;
    __syncthreads();
    for (int e = tid; e < EE; e += 256) {
        const int s = edge_index[e], d = edge_index[EE + e];
        if (s == v) atomicOr(&bits[d >> 5], 1u << (d & 31));
        if (d == v) atomicOr(&bits[s >> 5], 1u << (s & 31));
    }
    __syncthreads();
    if (tid == 0) {
        int cnt = 0;
        for (int w = 0; w < 16; ++w) {
            unsigned int b = bits[w];
            while (b) {
                const int j = __ffs(b) - 1;
                b &= b - 1u;
                if (cnt < MAXD) g_nbrs64[v][cnt++] = w * 32 + j;   // ascending = sorted set
            }
        }
        g_degs[v] = cnt;
    }
}

// ---------------- schedule expansion + phase lists: single block, all-LDS ----------------
__global__ __launch_bounds__(1024) void k_sched(const int* __restrict__ starts) {
    __shared__ int s_nx[MAX_STEPS];      // 20 KB node per step
    __shared__ int s_ny[MAX_STEPS];      // 20 KB enqueue base per step
    __shared__ int scanbuf[2][1024];     // 8 KB
    __shared__ int s_deg[NN];
    __shared__ int s_off[NN + 1];
    __shared__ int s_csr[4160];          // 16 KB compact neighbor lists
    __shared__ int s_nodes[NN];
    __shared__ int s_cnt[NN];
    __shared__ int s_grp[NN];
    __shared__ int s_misc[4];
    const int tid = threadIdx.x;

    if (tid < NN) { s_deg[tid] = g_degs[tid]; s_cnt[tid] = starts[tid]; }
    for (int i = tid; i < MAX_STEPS; i += 1024) s_ny[i] = 0x7fffffff;
    __syncthreads();
    if (tid == 0) {
        int off = 0;
        for (int v = 0; v < NN; ++v) { s_off[v] = off; off += s_deg[v]; }
        s_off[NN] = off;
        int s0 = 0;
        for (int n = 0; n < NN; ++n) if (s_cnt[n] != 0) s_nodes[s0++] = n;
        s_misc[0] = s0;
    }
    __syncthreads();
    // stage compact CSR into LDS
    if (tid < NN) {
        const int o = s_off[tid], dg = s_deg[tid];
        for (int e = 0; e < dg; ++e) s_csr[o + e] = g_nbrs64[tid][e];
    }
    const int S0 = s_misc[0];
    int known = (S0 < MAX_STEPS) ? S0 : MAX_STEPS;
    for (int i = tid; i < known; i += 1024) s_nx[i] = s_nodes[i];
    __syncthreads();

    // round-expansion (message-independent), all in LDS
    for (int round = 0; round < 8 && known > 0; ++round) {
        const int C = (known + 1023) >> 10;
        const int base = tid * C;
        int lsum = 0;
        for (int j = 0; j < C; ++j) {
            int i = base + j;
            if (i < known) lsum += s_deg[s_nx[i]];
        }
        scanbuf[0][tid] = lsum;
        __syncthreads();
        int src = 0;
        for (int off = 1; off < 1024; off <<= 1) {
            int v = scanbuf[src][tid];
            if (tid >= off) v += scanbuf[src][tid - off];
            scanbuf[src ^ 1][tid] = v;
            src ^= 1;
            __syncthreads();
        }
        const int excl = (tid == 0) ? 0 : scanbuf[src][tid - 1];
        const int total = scanbuf[src][1023];
        int t = S0 + excl;
        for (int j = 0; j < C; ++j) {
            int i = base + j;
            if (i < known) {
                const int nd = s_nx[i];
                const int dg = s_deg[nd], o = s_off[nd];
                s_ny[i] = t;
                for (int e = 0; e < dg; ++e) {
                    const int pos = t + e;
                    if (pos >= known && pos < MAX_STEPS) s_nx[pos] = s_csr[o + e];
                }
                t += dg;
            }
        }
        __syncthreads();
        int newknown = S0 + total;
        if (newknown > MAX_STEPS) newknown = MAX_STEPS;
        if (newknown == known) break;
        known = newknown;
    }
    __syncthreads();
    const int kn = known;
    if (tid == 0) s_misc[1] = kn;
    __syncthreads();
    for (int i = tid; i < kn; i += 1024)
        if (s_ny[i] <= i) atomicMin(&s_misc[1], i);        // first drained step
    __syncthreads();
    const int istar = s_misc[1];
    if (tid == 0) s_misc[2] = istar;
    __syncthreads();
    for (int i = tid; i < istar; i += 1024)
        if (s_ny[i] >= istar) atomicMin(&s_misc[2], i);    // first step producing nothing consumed
    __syncthreads();
    const int P = s_misc[2];

    // write out schedule (coalesced int4)
    for (int i = tid; i < MAX_STEPS; i += 1024) {
        int4 sc;
        if (i < kn) { sc.x = s_nx[i]; sc.y = s_ny[i]; sc.z = s_deg[sc.x]; }
        else { sc.x = 0; sc.y = 0x7fffffff; sc.z = 0; }
        sc.w = 0;
        g_sched[i] = sc;
    }
    if (tid == 0) { g_S0 = S0; g_T = istar; }

    // phase-A per-WG lists (node & 255 ownership, ascending step order)
    if (tid < NWGA) {
        int c = 0;
        for (int i = 0; i < P; ++i)
            if ((s_nx[i] & (NWGA - 1)) == tid) g_alist[tid][c++] = i;
        g_acnt[tid] = c;
    }
    // phase-B per-node counts
    if (tid < NN) s_cnt[tid] = 0;
    __syncthreads();
    for (int i = P + tid; i < istar; i += 1024) atomicAdd(&s_cnt[s_nx[i]], 1);
    __syncthreads();
    if (tid == 0) {
        int off = 0;
        for (int v = 0; v < NN; ++v) { s_off[v] = off; off += s_cnt[v]; }   // reuse s_off
        s_off[NN] = off;
    }
    __syncthreads();
    if (tid <= NN) g_noff[tid] = s_off[tid];
    if (tid < NN) {
        int c = s_off[tid];
        for (int i = P; i < istar; ++i)
            if (s_nx[i] == tid) g_nlist[c++] = i;
    }
    __syncthreads();
    // greedy least-loaded node -> phase-B WG assignment (64-lane wave argmin)
    if (tid < 64) {
        int ld0 = 0, ld1 = 0;
        for (int v = 0; v < NN; ++v) {
            const int c = s_cnt[v];
            const int sub = (ld1 < ld0) ? 1 : 0;
            const int myload = sub ? ld1 : ld0;
            int key = myload * 256 + (tid * 2 + sub);
#pragma unroll
            for (int off = 32; off >= 1; off >>= 1) {
                int ok = __shfl_xor(key, off);
                key = (ok < key) ? ok : key;
            }
            const int gid = key & 255;
            if ((gid >> 1) == tid) { if (gid & 1) ld1 += c; else ld0 += c; }
            if (tid == 0) s_grp[v] = gid;
        }
    }
    __syncthreads();
    if (tid < NWGB) {
        int c = 0;
        for (int v = 0; v < NN; ++v)
            if (s_grp[v] == tid && s_cnt[v] > 0) g_bq[tid][c++] = v;
        g_bqcnt[tid] = c;
    }
    for (int i = tid; i < MAX_STEPS; i += 1024) g_mready[i] = (i < S0) ? 1 : 0;
}

// ---------------- initial queue messages (parallel copy) ----------------
__global__ __launch_bounds__(128) void k_qinit(const float* __restrict__ first_message) {
    const int i = blockIdx.x;
    if (i >= g_S0) return;
    const int node = g_sched[i].x;
    g_qmsgs[i][threadIdx.x] = first_message[node * MSGD + threadIdx.x];
}

// ---------------- phase A: fence-free dataflow over steps [0, P) ----------------
__global__ __launch_bounds__(512, 1) void k_phaseA(const float* __restrict__ nm_b) {
    __shared__ float sAct[MSGD];
    __shared__ float sNH[2][HID], sNC[2][HID];
    __shared__ float sGates[1024];
    __shared__ float sPart[4 * MSGD];
    const int tid = threadIdx.x, wg = blockIdx.x;
    const int cntA = g_acnt[wg];
    if (cntA == 0) return;
    const int S0 = g_S0, T = g_T;
    const float vb0 = g_bias[2 * tid], vb1 = g_bias[2 * tid + 1];
    const float2* WT2 = (const float2*)g_WT;

    // my two candidate nodes: wg and wg+256
    for (int idx = tid; idx < 2 * HID; idx += 512) {
        int sl = idx >> 8, u = idx & 255, v = wg + (sl << 8);
        sNH[sl][u] = g_hid[v][u];
        sNC[sl][u] = g_cell[v][u];
    }
    __syncthreads();

    for (int k = 0; k < cntA; ++k) {
        const int s = g_alist[wg][k];
        const int4 sc = g_sched[s];
        const int node = sc.x, y = sc.y, deg = sc.z, sl = node >> 8;
        if (s >= S0) {
            if (tid == 0) {
                while (__hip_atomic_load(&g_mready[s], __ATOMIC_RELAXED,
                                         __HIP_MEMORY_SCOPE_AGENT) == 0)
                    __builtin_amdgcn_s_sleep(2);
            }
            __syncthreads();
            __builtin_amdgcn_fence(__ATOMIC_ACQUIRE, "workgroup");  // compiler/wave order only
        }
        // stage message (coherent scalar loads bypass stale L1/L2)
        if (tid < MSGD) {
            sAct[tid] = (s < S0) ? g_qmsgs[s][tid]
                                 : __hip_atomic_load(&g_qmsgs[s][tid], __ATOMIC_RELAXED,
                                                     __HIP_MEMORY_SCOPE_AGENT);
        }
        __syncthreads();
        // gates: rows 2t, 2t+1 via transposed weights (coalesced float2 per lane)
        {
            float acc0 = vb0, acc1 = vb1;
#pragma unroll 8
            for (int c = 0; c < MSGD; ++c) {
                const float2 w = WT2[c * 512 + tid];
                const float a = sAct[c];
                acc0 += w.x * a; acc1 += w.y * a;
            }
#pragma unroll 8
            for (int c = 0; c < HID; ++c) {
                const float2 w = WT2[(MSGD + c) * 512 + tid];
                const float h = sNH[sl][c];
                acc0 += w.x * h; acc1 += w.y * h;
            }
            ((float2*)sGates)[tid] = make_float2(acc0, acc1);
        }
        __syncthreads();
        // LSTM cell (torch order i,f,g,o)
        if (tid < HID) {
            const int u = tid;
            const float gi = sGates[u], gf = sGates[256 + u];
            const float gg = sGates[512 + u], go = sGates[768 + u];
            const float cp = sNC[sl][u];
            const float cn = sigm(gf) * cp + sigm(gi) * tanhf(gg);
            const float hn = sigm(go) * tanhf(cn);
            sNC[sl][u] = cn;
            sNH[sl][u] = hn;
        }
        __syncthreads();
        // nm partials: output o = tid&127, column-quarter cq = tid>>7
        {
            const int o = tid & (MSGD - 1), cq = tid >> 7;
            float p = 0.0f;
#pragma unroll 8
            for (int j = 0; j < 96; ++j) {
                const int c = cq + 4 * j;
                const float a = (c < HID) ? sNH[sl][c] : sAct[c - HID];
                p += g_nmT[c * MSGD + o] * a;
            }
            sPart[cq * MSGD + o] = p;
        }
        __syncthreads();
        const int lim = (y + deg <= T) ? deg : (T - y);
        if (tid < MSGD) {
            const float m = nm_b[tid] + sPart[tid] + sPart[MSGD + tid]
                          + sPart[2 * MSGD + tid] + sPart[3 * MSGD + tid];
            for (int e = 0; e < lim; ++e)
                __hip_atomic_store(&g_qmsgs[y + e][tid], m, __ATOMIC_RELAXED,
                                   __HIP_MEMORY_SCOPE_AGENT);
        }
        __syncthreads();   // drains every wave's stores before flags
        if (tid < lim)
            __hip_atomic_store(&g_mready[y + tid], 1, __ATOMIC_RELAXED,
                               __HIP_MEMORY_SCOPE_AGENT);
    }
    __syncthreads();
    for (int idx = tid; idx < 2 * HID; idx += 512) {
        int sl = idx >> 8, u = idx & 255, v = wg + (sl << 8);
        g_hid[v][u]  = sNH[sl][u];
        g_cell[v][u] = sNC[sl][u];
    }
}

// ---------------- phase B: independent per-node chains, KB slots in lockstep ----------------
__global__ __launch_bounds__(512, 1) void k_phaseB() {
    __shared__ float sAct[KB][MSGD];
    __shared__ float sH[KB][HID], sC[KB][HID];
    __shared__ float sGates[KB][1024];
    __shared__ int sNode[KB], sPos[KB], sEnd[KB], sStep[KB], sFill[KB], sDrain[KB];
    __shared__ int sMeta[2];   // [0]=anyActive, [1]=queue pos
    const int tid = threadIdx.x, wg = blockIdx.x;
    const int qcnt = g_bqcnt[wg];
    const float vb0 = g_bias[2 * tid], vb1 = g_bias[2 * tid + 1];
    const float2* WT2 = (const float2*)g_WT;

    if (tid == 0) {
        int qp = 0;
        for (int k = 0; k < KB; ++k) {
            if (qp < qcnt) {
                int v = g_bq[wg][qp++];
                sNode[k] = v; sPos[k] = g_noff[v]; sEnd[k] = g_noff[v + 1]; sFill[k] = v;
            } else { sNode[k] = -1; sFill[k] = -1; }
            sDrain[k] = -1;
        }
        sMeta[1] = qp;
    }
    __syncthreads();
    for (int idx = tid; idx < KB * HID; idx += 512) {
        int k = idx >> 8, u = idx & 255, v = sFill[k];
        if (v >= 0) { sH[k][u] = g_hid[v][u]; sC[k][u] = g_cell[v][u]; }
    }
    __syncthreads();

    while (true) {
        if (tid == 0) {
            int any = 0;
            for (int k = 0; k < KB; ++k) {
                if (sNode[k] >= 0) { sStep[k] = g_nlist[sPos[k]]; any = 1; }
                else sStep[k] = -1;
            }
            sMeta[0] = any;
        }
        __syncthreads();
        if (!sMeta[0]) break;
        // stage messages (written in phase A, visible cross-kernel)
        for (int idx = tid; idx < KB * (MSGD / 4); idx += 512) {
            int k = idx >> 5, c4 = idx & 31, s = sStep[k];
            if (s >= 0) ((float4*)sAct[k])[c4] = ((const float4*)g_qmsgs[s])[c4];
        }
        __syncthreads();
        // gates: rows 2t,2t+1 x KB columns, coalesced transposed weights
        {
            float acc0[KB], acc1[KB];
#pragma unroll
            for (int k = 0; k < KB; ++k) { acc0[k] = vb0; acc1[k] = vb1; }
#pragma unroll 4
            for (int c = 0; c < MSGD; ++c) {
                const float2 w = WT2[c * 512 + tid];
#pragma unroll
                for (int k = 0; k < KB; ++k) {
                    const float a = sAct[k][c];
                    acc0[k] += w.x * a; acc1[k] += w.y * a;
                }
            }
#pragma unroll 4
            for (int c = 0; c < HID; ++c) {
                const float2 w = WT2[(MSGD + c) * 512 + tid];
#pragma unroll
                for (int k = 0; k < KB; ++k) {
                    const float h = sH[k][c];
                    acc0[k] += w.x * h; acc1[k] += w.y * h;
                }
            }
#pragma unroll
            for (int k = 0; k < KB; ++k)
                ((float2*)sGates[k])[tid] = make_float2(acc0[k], acc1[k]);
        }
        __syncthreads();
        // cell update in LDS
        for (int idx = tid; idx < KB * HID; idx += 512) {
            int k = idx >> 8, u = idx & 255;
            if (sStep[k] >= 0) {
                const float gi = sGates[k][u], gf = sGates[k][256 + u];
                const float gg = sGates[k][512 + u], go = sGates[k][768 + u];
                const float cp = sC[k][u];
                const float cn = sigm(gf) * cp + sigm(gi) * tanhf(gg);
                const float hn = sigm(go) * tanhf(cn);
                sC[k][u] = cn;
                sH[k][u] = hn;
            }
        }
        if (tid == 0) {
            int qp = sMeta[1];
            for (int k = 0; k < KB; ++k) {
                sDrain[k] = -1; sFill[k] = -1;
                if (sStep[k] >= 0 && ++sPos[k] == sEnd[k]) {
                    sDrain[k] = sNode[k];
                    if (qp < qcnt) {
                        int v = g_bq[wg][qp++];
                        sNode[k] = v; sPos[k] = g_noff[v]; sEnd[k] = g_noff[v + 1]; sFill[k] = v;
                    } else sNode[k] = -1;
                }
            }
            sMeta[1] = qp;
        }
        __syncthreads();
        for (int idx = tid; idx < KB * HID; idx += 512) {
            int k = idx >> 8, u = idx & 255, v = sDrain[k];
            if (v >= 0) g_hid[v][u] = sH[k][u];
        }
        __syncthreads();
        for (int idx = tid; idx < KB * HID; idx += 512) {
            int k = idx >> 8, u = idx & 255, v = sFill[k];
            if (v >= 0) { sH[k][u] = g_hid[v][u]; sC[k][u] = g_cell[v][u]; }
        }
        __syncthreads();
    }
}

// ---------------- decoder: logits + log_softmax ----------------
__global__ __launch_bounds__(256) void k_decode(const float* __restrict__ dec_W,
                                                const float* __restrict__ dec_b,
                                                float* __restrict__ out) {
    const int gtid = blockIdx.x * 256 + threadIdx.x;
    const int row = gtid >> 4, lane = gtid & 15;   // row = p*NN + n
    const int p = row >> 9, n = row & (NN - 1);
    const float* dw = dec_W + (p * OUTC + lane) * HID;
    float acc = dec_b[p * OUTC + lane];
#pragma unroll 8
    for (int j = 0; j < HID; j += 4) {
        const float4 hv = *(const float4*)&g_hid[n][j];
        const float4 wv = *(const float4*)(dw + j);
        acc += hv.x * wv.x + hv.y * wv.y + hv.z * wv.z + hv.w * wv.w;
    }
    float mx = acc;
    mx = fmaxf(mx, __shfl_xor(mx, 1));
    mx = fmaxf(mx, __shfl_xor(mx, 2));
    mx = fmaxf(mx, __shfl_xor(mx, 4));
    mx = fmaxf(mx, __shfl_xor(mx, 8));
    float s = expf(acc - mx);
    s += __shfl_xor(s, 1);
    s += __shfl_xor(s, 2);
    s += __shfl_xor(s, 4);
    s += __shfl_xor(s, 8);
    out[row * OUTC + lane] = acc - mx - logf(s);
}

extern "C" void kernel_launch(void* const* d_in, const int* in_sizes, int n_in,
                              void* d_out, int out_size, void* d_ws, size_t ws_size,
                              hipStream_t stream) {
    (void)in_sizes; (void)n_in; (void)out_size; (void)d_ws; (void)ws_size;
    const float* xa   = (const float*)d_in[0];
    const float* fm   = (const float*)d_in[1];
    const int*   ei   = (const int*)d_in[2];
    const int*   st   = (const int*)d_in[3];
    const float* encW = (const float*)d_in[4];
    const float* encb = (const float*)d_in[5];
    const float* Wih  = (const float*)d_in[6];
    const float* Whh  = (const float*)d_in[7];
    const float* bih  = (const float*)d_in[8];
    const float* bhh  = (const float*)d_in[9];
    const float* nmW  = (const float*)d_in[10];
    const float* nmb  = (const float*)d_in[11];
    const float* decW = (const float*)d_in[12];
    const float* decb = (const float*)d_in[13];
    float* out = (float*)d_out;

    hipLaunchKernelGGL(k_encoder, dim3(512),  dim3(256),  0, stream, xa, encW, encb);
    hipLaunchKernelGGL(k_prep,    dim3(384),  dim3(256),  0, stream, Wih, Whh, bih, bhh, nmW);
    hipLaunchKernelGGL(k_nbr,     dim3(NN),   dim3(256),  0, stream, ei);
    hipLaunchKernelGGL(k_sched,   dim3(1),    dim3(1024), 0, stream, st);
    hipLaunchKernelGGL(k_qinit,   dim3(512),  dim3(128),  0, stream, fm);
    hipLaunchKernelGGL(k_phaseA,  dim3(NWGA), dim3(512),  0, stream, nmb);
    hipLaunchKernelGGL(k_phaseB,  dim3(NWGB), dim3(512),  0, stream);
    hipLaunchKernelGGL(k_decode,  dim3(128),  dim3(256),  0, stream, decW, decb, out);
}

// Round 6
// 736.862 us; speedup vs baseline: 47.2963x; 2.0831x over previous
//
#include <hip/hip_runtime.h>
#include <math.h>

// ---------------- problem constants ----------------
#define NN 512
#define EE 2048
#define IN_F 64
#define HID 256
#define MSGD 128
#define OUTC 16
#define MAX_STEPS 5120

// ---------------- kernel config ----------------
#define NWGA 256      // phase-A WGs (node & 255 ownership)
#define MAXD 64       // padded neighbor-row stride

typedef _Float16 h2v __attribute__((ext_vector_type(2)));

static __device__ __forceinline__ float fdot2u(unsigned int w, unsigned int a, float c) {
    return __builtin_amdgcn_fdot2(__builtin_bit_cast(h2v, w),
                                  __builtin_bit_cast(h2v, a), c, false);
}
static __device__ __forceinline__ unsigned int pkh(float a, float b) {
    h2v h; h.x = (_Float16)a; h.y = (_Float16)b;     // RTN converts
    return __builtin_bit_cast(unsigned int, h);
}

// ---------------- device globals (all rewritten every call) ----------------
__device__ int   g_nbrs64[NN][MAXD];
__device__ int   g_degs[NN];
__device__ int4  g_sched[MAX_STEPS];     // x=node, y=t(enqueue base), z=deg
__device__ int   g_mready[MAX_STEPS];
__device__ int   g_S0, g_T;
__device__ int   g_alist[NWGA][MAX_STEPS];
__device__ int   g_acnt[NWGA];
__device__ int   g_noff[NN + 1];
__device__ int   g_nlist[MAX_STEPS];     // phase-B steps grouped by node
__device__ float g_qmsgs[MAX_STEPS][MSGD];
__device__ float g_hid[NN][HID];
__device__ float g_cell[NN][HID];
__device__ uint4 g_WTph[96 * 512];       // f16-packed gates: [colquad q][rowpair r]
                                         //  .x=(w[2r][4q],w[2r][4q+1]) .y=row 2r+1 same cols
                                         //  .z=(w[2r][4q+2],w[2r][4q+3]) .w=row 2r+1
__device__ unsigned int g_nmTph[192 * 128]; // f16-packed nm: [colpair cp][out o]
__device__ float g_bias[1024];           // b_ih + b_hh

__device__ __forceinline__ float sigm(float x) { return 1.0f / (1.0f + expf(-x)); }

// ---------------- encoder: hid = xa @ enc_W^T + enc_b ; cell = 0 ----------------
__global__ __launch_bounds__(256) void k_encoder(const float* __restrict__ xa,
                                                 const float* __restrict__ enc_W,
                                                 const float* __restrict__ enc_b) {
    int gid = blockIdx.x * 256 + threadIdx.x;
    int n = gid >> 8, c = gid & 255;
    const float* x = xa + n * IN_F;
    const float* w = enc_W + c * IN_F;
    float acc = enc_b[c];
#pragma unroll 8
    for (int j = 0; j < IN_F; ++j) acc += x[j] * w[j];
    g_hid[n][c] = acc;
    g_cell[n][c] = 0.0f;
}

// ---------------- prep: pack weights to f16 tiles ----------------
__device__ __forceinline__ float gw(const float* W_ih, const float* W_hh, int row, int c) {
    return (c < MSGD) ? W_ih[row * MSGD + c] : W_hh[row * HID + (c - MSGD)];
}
__global__ __launch_bounds__(256) void k_prep(const float* __restrict__ W_ih,
                                              const float* __restrict__ W_hh,
                                              const float* __restrict__ b_ih,
                                              const float* __restrict__ b_hh,
                                              const float* __restrict__ nm_W) {
    const int r = blockIdx.x;          // row-pair 0..511
    const int t = threadIdx.x;
    for (int q = t; q < 96; q += 256) {
        uint4 v;
        v.x = pkh(gw(W_ih, W_hh, 2 * r, 4 * q),     gw(W_ih, W_hh, 2 * r, 4 * q + 1));
        v.y = pkh(gw(W_ih, W_hh, 2 * r + 1, 4 * q), gw(W_ih, W_hh, 2 * r + 1, 4 * q + 1));
        v.z = pkh(gw(W_ih, W_hh, 2 * r, 4 * q + 2), gw(W_ih, W_hh, 2 * r, 4 * q + 3));
        v.w = pkh(gw(W_ih, W_hh, 2 * r + 1, 4 * q + 2), gw(W_ih, W_hh, 2 * r + 1, 4 * q + 3));
        g_WTph[q * 512 + r] = v;
    }
    if (r < 192 && t < 128)            // nm: concat cols [h(256)|msg(128)] = nm_W native
        g_nmTph[r * 128 + t] = pkh(nm_W[t * 384 + 2 * r], nm_W[t * 384 + 2 * r + 1]);
    if (r == 0)
        for (int g = t; g < 1024; g += 256) g_bias[g] = b_ih[g] + b_hh[g];
}

// ---------------- neighbor lists: one block per node ----------------
__global__ __launch_bounds__(256) void k_nbr(const int* __restrict__ edge_index) {
    __shared__ unsigned int bits[16];
    const int v = blockIdx.x, tid = threadIdx.x;
    if (tid < 16) bits[tid] = 0u;
    __syncthreads();
    for (int e = tid; e < EE; e += 256) {
        const int s = edge_index[e], d = edge_index[EE + e];
        if (s == v) atomicOr(&bits[d >> 5], 1u << (d & 31));
        if (d == v) atomicOr(&bits[s >> 5], 1u << (s & 31));
    }
    __syncthreads();
    if (tid == 0) {
        int cnt = 0;
        for (int w = 0; w < 16; ++w) {
            unsigned int b = bits[w];
            while (b) {
                const int j = __ffs(b) - 1;
                b &= b - 1u;
                if (cnt < MAXD) g_nbrs64[v][cnt++] = w * 32 + j;
            }
        }
        g_degs[v] = cnt;
    }
}

// ---------------- schedule expansion + phase lists: single block, all-LDS ----------------
__global__ __launch_bounds__(1024) void k_sched(const int* __restrict__ starts) {
    __shared__ int s_nx[MAX_STEPS];
    __shared__ int s_ny[MAX_STEPS];
    __shared__ int scanbuf[2][1024];
    __shared__ int s_deg[NN];
    __shared__ int s_off[NN + 1];
    __shared__ int s_csr[4160];
    __shared__ int s_nodes[NN];
    __shared__ int s_cnt[NN];
    __shared__ int s_misc[4];
    const int tid = threadIdx.x;

    if (tid < NN) { s_deg[tid] = g_degs[tid]; s_cnt[tid] = starts[tid]; }
    for (int i = tid; i < MAX_STEPS; i += 1024) s_ny[i] = 0x7fffffff;
    __syncthreads();
    if (tid == 0) {
        int off = 0;
        for (int v = 0; v < NN; ++v) { s_off[v] = off; off += s_deg[v]; }
        s_off[NN] = off;
        int s0 = 0;
        for (int n = 0; n < NN; ++n) if (s_cnt[n] != 0) s_nodes[s0++] = n;
        s_misc[0] = s0;
    }
    __syncthreads();
    if (tid < NN) {
        const int o = s_off[tid], dg = s_deg[tid];
        for (int e = 0; e < dg; ++e) s_csr[o + e] = g_nbrs64[tid][e];
    }
    const int S0 = s_misc[0];
    int known = (S0 < MAX_STEPS) ? S0 : MAX_STEPS;
    for (int i = tid; i < known; i += 1024) s_nx[i] = s_nodes[i];
    __syncthreads();

    for (int round = 0; round < 8 && known > 0; ++round) {
        const int C = (known + 1023) >> 10;
        const int base = tid * C;
        int lsum = 0;
        for (int j = 0; j < C; ++j) {
            int i = base + j;
            if (i < known) lsum += s_deg[s_nx[i]];
        }
        scanbuf[0][tid] = lsum;
        __syncthreads();
        int src = 0;
        for (int off = 1; off < 1024; off <<= 1) {
            int v = scanbuf[src][tid];
            if (tid >= off) v += scanbuf[src][tid - off];
            scanbuf[src ^ 1][tid] = v;
            src ^= 1;
            __syncthreads();
        }
        const int excl = (tid == 0) ? 0 : scanbuf[src][tid - 1];
        const int total = scanbuf[src][1023];
        int t = S0 + excl;
        for (int j = 0; j < C; ++j) {
            int i = base + j;
            if (i < known) {
                const int nd = s_nx[i];
                const int dg = s_deg[nd], o = s_off[nd];
                s_ny[i] = t;
                for (int e = 0; e < dg; ++e) {
                    const int pos = t + e;
                    if (pos >= known && pos < MAX_STEPS) s_nx[pos] = s_csr[o + e];
                }
                t += dg;
            }
        }
        __syncthreads();
        int newknown = S0 + total;
        if (newknown > MAX_STEPS) newknown = MAX_STEPS;
        if (newknown == known) break;
        known = newknown;
    }
    __syncthreads();
    const int kn = known;
    if (tid == 0) s_misc[1] = kn;
    __syncthreads();
    for (int i = tid; i < kn; i += 1024)
        if (s_ny[i] <= i) atomicMin(&s_misc[1], i);        // first drained step
    __syncthreads();
    const int istar = s_misc[1];
    if (tid == 0) s_misc[2] = istar;
    __syncthreads();
    for (int i = tid; i < istar; i += 1024)
        if (s_ny[i] >= istar) atomicMin(&s_misc[2], i);    // first nothing-consumed producer
    __syncthreads();
    const int P = s_misc[2];

    for (int i = tid; i < MAX_STEPS; i += 1024) {
        int4 sc;
        if (i < kn) { sc.x = s_nx[i]; sc.y = s_ny[i]; sc.z = s_deg[sc.x]; }
        else { sc.x = 0; sc.y = 0x7fffffff; sc.z = 0; }
        sc.w = 0;
        g_sched[i] = sc;
    }
    if (tid == 0) { g_S0 = S0; g_T = istar; }

    // phase-A per-WG lists (node & 255)
    if (tid < NWGA) {
        int c = 0;
        for (int i = 0; i < P; ++i)
            if ((s_nx[i] & (NWGA - 1)) == tid) g_alist[tid][c++] = i;
        g_acnt[tid] = c;
    }
    // phase-B per-node CSR
    if (tid < NN) s_cnt[tid] = 0;
    __syncthreads();
    for (int i = P + tid; i < istar; i += 1024) atomicAdd(&s_cnt[s_nx[i]], 1);
    __syncthreads();
    if (tid == 0) {
        int off = 0;
        for (int v = 0; v < NN; ++v) { s_off[v] = off; off += s_cnt[v]; }
        s_off[NN] = off;
    }
    __syncthreads();
    if (tid <= NN) g_noff[tid] = s_off[tid];
    if (tid < NN) {
        int c = s_off[tid];
        for (int i = P; i < istar; ++i)
            if (s_nx[i] == tid) g_nlist[c++] = i;
    }
    for (int i = tid; i < MAX_STEPS; i += 1024) g_mready[i] = (i < S0) ? 1 : 0;
}

// ---------------- initial queue messages ----------------
__global__ __launch_bounds__(128) void k_qinit(const float* __restrict__ first_message) {
    const int i = blockIdx.x;
    if (i >= g_S0) return;
    const int node = g_sched[i].x;
    g_qmsgs[i][threadIdx.x] = first_message[node * MSGD + threadIdx.x];
}

// ---------------- phase A: fence-free dataflow over steps [0, P) ----------------
__global__ __launch_bounds__(512, 1) void k_phaseA(const float* __restrict__ nm_b) {
    __shared__ float sAct[MSGD];
    __shared__ float sNH[2][HID], sNC[2][HID];
    __shared__ float sGates[1024];
    __shared__ float sPart[4 * MSGD];
    __shared__ unsigned int sActP[192];    // gate acts packed: [msg(64) | h(128)] pairs
    __shared__ unsigned int sActN[192];    // nm acts packed:   [h(128) | msg(64)] pairs
    const int tid = threadIdx.x, wg = blockIdx.x;
    const int cntA = g_acnt[wg];
    if (cntA == 0) return;
    const int S0 = g_S0, T = g_T;
    const float vb0 = g_bias[2 * tid], vb1 = g_bias[2 * tid + 1];

    for (int idx = tid; idx < 2 * HID; idx += 512) {
        int sl = idx >> 8, u = idx & 255, v = wg + (sl << 8);
        sNH[sl][u] = g_hid[v][u];
        sNC[sl][u] = g_cell[v][u];
    }
    __syncthreads();

    for (int k = 0; k < cntA; ++k) {
        const int s = g_alist[wg][k];
        const int4 sc = g_sched[s];
        const int node = sc.x, y = sc.y, deg = sc.z, sl = node >> 8;
        if (s >= S0) {
            if (tid == 0) {
                while (__hip_atomic_load(&g_mready[s], __ATOMIC_RELAXED,
                                         __HIP_MEMORY_SCOPE_AGENT) == 0)
                    __builtin_amdgcn_s_sleep(2);
            }
            __syncthreads();
            __builtin_amdgcn_fence(__ATOMIC_ACQUIRE, "workgroup");
        }
        // stage message + pack; pack h_prev
        if (tid < 64) {
            float a0, a1;
            if (s < S0) { a0 = g_qmsgs[s][2 * tid]; a1 = g_qmsgs[s][2 * tid + 1]; }
            else {
                a0 = __hip_atomic_load(&g_qmsgs[s][2 * tid],     __ATOMIC_RELAXED,
                                       __HIP_MEMORY_SCOPE_AGENT);
                a1 = __hip_atomic_load(&g_qmsgs[s][2 * tid + 1], __ATOMIC_RELAXED,
                                       __HIP_MEMORY_SCOPE_AGENT);
            }
            sAct[2 * tid] = a0; sAct[2 * tid + 1] = a1;
            sActP[tid] = pkh(a0, a1);
        } else if (tid < 192) {
            const int j = tid - 64;
            sActP[tid] = pkh(sNH[sl][2 * j], sNH[sl][2 * j + 1]);
        }
        __syncthreads();
        // gates: rows (2t, 2t+1), 96 x uint4 f16 tiles
        {
            float acc0 = vb0, acc1 = vb1;
#pragma unroll 8
            for (int q = 0; q < 96; ++q) {
                const uint4 w = g_WTph[q * 512 + tid];
                const unsigned int a01 = sActP[2 * q], a23 = sActP[2 * q + 1];
                acc0 = fdot2u(w.x, a01, acc0); acc1 = fdot2u(w.y, a01, acc1);
                acc0 = fdot2u(w.z, a23, acc0); acc1 = fdot2u(w.w, a23, acc1);
            }
            ((float2*)sGates)[tid] = make_float2(acc0, acc1);
        }
        __syncthreads();
        // LSTM cell (torch order i,f,g,o)
        if (tid < HID) {
            const int u = tid;
            const float gi = sGates[u], gf = sGates[256 + u];
            const float gg = sGates[512 + u], go = sGates[768 + u];
            const float cp = sNC[sl][u];
            const float cn = sigm(gf) * cp + sigm(gi) * tanhf(gg);
            const float hn = sigm(go) * tanhf(cn);
            sNC[sl][u] = cn;
            sNH[sl][u] = hn;
        }
        __syncthreads();
        // pack nm acts: [h_new(256) | msg(128)]
        if (tid < 128) sActN[tid] = pkh(sNH[sl][2 * tid], sNH[sl][2 * tid + 1]);
        else if (tid < 192) {
            const int j = tid - 128;
            sActN[tid] = pkh(sAct[2 * j], sAct[2 * j + 1]);
        }
        __syncthreads();
        // nm partials: o = tid&127, col-quarter cq = tid>>7 covers 48 pairs
        {
            const int o = tid & (MSGD - 1), cq = tid >> 7;
            float p = 0.0f;
#pragma unroll 8
            for (int j = 0; j < 48; ++j) {
                const int cp = 48 * cq + j;
                p = fdot2u(g_nmTph[cp * 128 + o], sActN[cp], p);
            }
            sPart[cq * MSGD + o] = p;
        }
        __syncthreads();
        const int lim = (y + deg <= T) ? deg : (T - y);
        if (tid < MSGD) {
            const float m = nm_b[tid] + sPart[tid] + sPart[MSGD + tid]
                          + sPart[2 * MSGD + tid] + sPart[3 * MSGD + tid];
            for (int e = 0; e < lim; ++e)
                __hip_atomic_store(&g_qmsgs[y + e][tid], m, __ATOMIC_RELAXED,
                                   __HIP_MEMORY_SCOPE_AGENT);
        }
        __syncthreads();   // drain all waves' stores before flags
        if (tid < lim)
            __hip_atomic_store(&g_mready[y + tid], 1, __ATOMIC_RELAXED,
                               __HIP_MEMORY_SCOPE_AGENT);
    }
    __syncthreads();
    for (int idx = tid; idx < 2 * HID; idx += 512) {
        int sl = idx >> 8, u = idx & 255, v = wg + (sl << 8);
        g_hid[v][u]  = sNH[sl][u];
        g_cell[v][u] = sNC[sl][u];
    }
}

// ---------------- phase B: one WG per node, serial chain, f16 gate stream ----------------
__global__ __launch_bounds__(512, 4) void k_phaseB() {
    __shared__ float sGates[1024];
    __shared__ float sH[HID], sC[HID];
    __shared__ unsigned int sActP[192];
    const int n = blockIdx.x, tid = threadIdx.x;
    int pos = g_noff[n];
    const int pend = g_noff[n + 1];
    if (pos >= pend) return;
    const float vb0 = g_bias[2 * tid], vb1 = g_bias[2 * tid + 1];

    if (tid < HID) { sH[tid] = g_hid[n][tid]; sC[tid] = g_cell[n][tid]; }
    __syncthreads();

    for (; pos < pend; ++pos) {
        const int s = g_nlist[pos];
        if (tid < 64) {
            const float2 m = *(const float2*)&g_qmsgs[s][2 * tid];
            sActP[tid] = pkh(m.x, m.y);
        } else if (tid < 192) {
            const int j = tid - 64;
            sActP[tid] = pkh(sH[2 * j], sH[2 * j + 1]);
        }
        __syncthreads();
        float acc0 = vb0, acc1 = vb1;
#pragma unroll 8
        for (int q = 0; q < 96; ++q) {
            const uint4 w = g_WTph[q * 512 + tid];
            const unsigned int a01 = sActP[2 * q], a23 = sActP[2 * q + 1];
            acc0 = fdot2u(w.x, a01, acc0); acc1 = fdot2u(w.y, a01, acc1);
            acc0 = fdot2u(w.z, a23, acc0); acc1 = fdot2u(w.w, a23, acc1);
        }
        ((float2*)sGates)[tid] = make_float2(acc0, acc1);
        __syncthreads();
        if (tid < HID) {
            const float gi = sGates[tid], gf = sGates[256 + tid];
            const float gg = sGates[512 + tid], go = sGates[768 + tid];
            const float cn = sigm(gf) * sC[tid] + sigm(gi) * tanhf(gg);
            sC[tid] = cn;
            sH[tid] = sigm(go) * tanhf(cn);
        }
        __syncthreads();
    }
    if (tid < HID) g_hid[n][tid] = sH[tid];
}

// ---------------- decoder: logits + log_softmax ----------------
__global__ __launch_bounds__(256) void k_decode(const float* __restrict__ dec_W,
                                                const float* __restrict__ dec_b,
                                                float* __restrict__ out) {
    const int gtid = blockIdx.x * 256 + threadIdx.x;
    const int row = gtid >> 4, lane = gtid & 15;   // row = p*NN + n
    const int p = row >> 9, n = row & (NN - 1);
    const float* dw = dec_W + (p * OUTC + lane) * HID;
    float acc = dec_b[p * OUTC + lane];
#pragma unroll 8
    for (int j = 0; j < HID; j += 4) {
        const float4 hv = *(const float4*)&g_hid[n][j];
        const float4 wv = *(const float4*)(dw + j);
        acc += hv.x * wv.x + hv.y * wv.y + hv.z * wv.z + hv.w * wv.w;
    }
    float mx = acc;
    mx = fmaxf(mx, __shfl_xor(mx, 1));
    mx = fmaxf(mx, __shfl_xor(mx, 2));
    mx = fmaxf(mx, __shfl_xor(mx, 4));
    mx = fmaxf(mx, __shfl_xor(mx, 8));
    float s = expf(acc - mx);
    s += __shfl_xor(s, 1);
    s += __shfl_xor(s, 2);
    s += __shfl_xor(s, 4);
    s += __shfl_xor(s, 8);
    out[row * OUTC + lane] = acc - mx - logf(s);
}

extern "C" void kernel_launch(void* const* d_in, const int* in_sizes, int n_in,
                              void* d_out, int out_size, void* d_ws, size_t ws_size,
                              hipStream_t stream) {
    (void)in_sizes; (void)n_in; (void)out_size; (void)d_ws; (void)ws_size;
    const float* xa   = (const float*)d_in[0];
    const float* fm   = (const float*)d_in[1];
    const int*   ei   = (const int*)d_in[2];
    const int*   st   = (const int*)d_in[3];
    const float* encW = (const float*)d_in[4];
    const float* encb = (const float*)d_in[5];
    const float* Wih  = (const float*)d_in[6];
    const float* Whh  = (const float*)d_in[7];
    const float* bih  = (const float*)d_in[8];
    const float* bhh  = (const float*)d_in[9];
    const float* nmW  = (const float*)d_in[10];
    const float* nmb  = (const float*)d_in[11];
    const float* decW = (const float*)d_in[12];
    const float* decb = (const float*)d_in[13];
    float* out = (float*)d_out;

    hipLaunchKernelGGL(k_encoder, dim3(512),  dim3(256),  0, stream, xa, encW, encb);
    hipLaunchKernelGGL(k_prep,    dim3(512),  dim3(256),  0, stream, Wih, Whh, bih, bhh, nmW);
    hipLaunchKernelGGL(k_nbr,     dim3(NN),   dim3(256),  0, stream, ei);
    hipLaunchKernelGGL(k_sched,   dim3(1),    dim3(1024), 0, stream, st);
    hipLaunchKernelGGL(k_qinit,   dim3(512),  dim3(128),  0, stream, fm);
    hipLaunchKernelGGL(k_phaseA,  dim3(NWGA), dim3(512),  0, stream, nmb);
    hipLaunchKernelGGL(k_phaseB,  dim3(NN),   dim3(512),  0, stream);
    hipLaunchKernelGGL(k_decode,  dim3(128),  dim3(256),  0, stream, decW, decb, out);
}

// Round 7
// 370.152 us; speedup vs baseline: 94.1528x; 1.9907x over previous
//
#include <hip/hip_runtime.h>
#include <math.h>

// ---------------- problem constants ----------------
#define NN 512
#define EE 2048
#define IN_F 64
#define HID 256
#define MSGD 128
#define OUTC 16
#define MAX_STEPS 5120

// ---------------- kernel config ----------------
#define NWGA 256      // phase-A WGs (node & 255 ownership)
#define MAXD 64       // padded neighbor-row stride

typedef _Float16 h2v __attribute__((ext_vector_type(2)));

static __device__ __forceinline__ float fdot2u(unsigned int w, unsigned int a, float c) {
    return __builtin_amdgcn_fdot2(__builtin_bit_cast(h2v, w),
                                  __builtin_bit_cast(h2v, a), c, false);
}
static __device__ __forceinline__ unsigned int pkh(float a, float b) {
    h2v h; h.x = (_Float16)a; h.y = (_Float16)b;     // RTN converts
    return __builtin_bit_cast(unsigned int, h);
}

// ---------------- device globals (all rewritten every call) ----------------
__device__ int   g_nbrs64[NN][MAXD];
__device__ int   g_degs[NN];
__device__ int4  g_sched[MAX_STEPS];     // x=node, y=t(enqueue base), z=deg
__device__ int   g_mready[MAX_STEPS];
__device__ int   g_S0, g_T, g_P;
__device__ int   g_alist[NWGA][MAX_STEPS];
__device__ int   g_acnt[NWGA];
__device__ int   g_noff[NN + 1];
__device__ int   g_nlist[MAX_STEPS];     // phase-B steps grouped by node
__device__ float g_qmsgs[MAX_STEPS][MSGD];
__device__ float g_hid[NN][HID];
__device__ float g_cell[NN][HID];
__device__ uint4 g_WTph[96 * 512];       // f16-packed gates: [colquad q][rowpair r]
__device__ unsigned int g_nmTph[192 * 128]; // f16-packed nm: [colpair cp][out o]
__device__ float g_bias[1024];           // b_ih + b_hh

__device__ __forceinline__ float sigm(float x) { return 1.0f / (1.0f + expf(-x)); }

// ---------------- encoder: hid = xa @ enc_W^T + enc_b ; cell = 0 ----------------
__global__ __launch_bounds__(256) void k_encoder(const float* __restrict__ xa,
                                                 const float* __restrict__ enc_W,
                                                 const float* __restrict__ enc_b) {
    int gid = blockIdx.x * 256 + threadIdx.x;
    int n = gid >> 8, c = gid & 255;
    const float* x = xa + n * IN_F;
    const float* w = enc_W + c * IN_F;
    float acc = enc_b[c];
#pragma unroll 8
    for (int j = 0; j < IN_F; ++j) acc += x[j] * w[j];
    g_hid[n][c] = acc;
    g_cell[n][c] = 0.0f;
}

// ---------------- prep: pack weights to f16 tiles ----------------
__device__ __forceinline__ float gw(const float* W_ih, const float* W_hh, int row, int c) {
    return (c < MSGD) ? W_ih[row * MSGD + c] : W_hh[row * HID + (c - MSGD)];
}
__global__ __launch_bounds__(256) void k_prep(const float* __restrict__ W_ih,
                                              const float* __restrict__ W_hh,
                                              const float* __restrict__ b_ih,
                                              const float* __restrict__ b_hh,
                                              const float* __restrict__ nm_W) {
    const int r = blockIdx.x;          // row-pair 0..511
    const int t = threadIdx.x;
    for (int q = t; q < 96; q += 256) {
        uint4 v;
        v.x = pkh(gw(W_ih, W_hh, 2 * r, 4 * q),     gw(W_ih, W_hh, 2 * r, 4 * q + 1));
        v.y = pkh(gw(W_ih, W_hh, 2 * r + 1, 4 * q), gw(W_ih, W_hh, 2 * r + 1, 4 * q + 1));
        v.z = pkh(gw(W_ih, W_hh, 2 * r, 4 * q + 2), gw(W_ih, W_hh, 2 * r, 4 * q + 3));
        v.w = pkh(gw(W_ih, W_hh, 2 * r + 1, 4 * q + 2), gw(W_ih, W_hh, 2 * r + 1, 4 * q + 3));
        g_WTph[q * 512 + r] = v;
    }
    if (r < 192 && t < 128)            // nm: concat cols [h(256)|msg(128)] = nm_W native
        g_nmTph[r * 128 + t] = pkh(nm_W[t * 384 + 2 * r], nm_W[t * 384 + 2 * r + 1]);
    if (r == 0)
        for (int g = t; g < 1024; g += 256) g_bias[g] = b_ih[g] + b_hh[g];
}

// ---------------- neighbor lists: one block per node ----------------
__global__ __launch_bounds__(256) void k_nbr(const int* __restrict__ edge_index) {
    __shared__ unsigned int bits[16];
    const int v = blockIdx.x, tid = threadIdx.x;
    if (tid < 16) bits[tid] = 0u;
    __syncthreads();
    for (int e = tid; e < EE; e += 256) {
        const int s = edge_index[e], d = edge_index[EE + e];
        if (s == v) atomicOr(&bits[d >> 5], 1u << (d & 31));
        if (d == v) atomicOr(&bits[s >> 5], 1u << (s & 31));
    }
    __syncthreads();
    if (tid == 0) {
        int cnt = 0;
        for (int w = 0; w < 16; ++w) {
            unsigned int b = bits[w];
            while (b) {
                const int j = __ffs(b) - 1;
                b &= b - 1u;
                if (cnt < MAXD) g_nbrs64[v][cnt++] = w * 32 + j;
            }
        }
        g_degs[v] = cnt;
    }
}

// ---------------- schedule expansion: single block, parallel scans ----------------
__global__ __launch_bounds__(1024) void k_sched(const int* __restrict__ starts) {
    __shared__ int s_nx[MAX_STEPS];
    __shared__ int s_ny[MAX_STEPS];
    __shared__ int scanbuf[2][1024];
    __shared__ int s_deg[NN];
    __shared__ int s_off[NN + 1];
    __shared__ int s_csr[4160];
    __shared__ int s_nodes[NN];
    __shared__ int s_cnt[NN];
    __shared__ int s_misc[4];
    const int tid = threadIdx.x;

    const int stt = (tid < NN && starts[tid] != 0) ? 1 : 0;
    const int dg0 = (tid < NN) ? g_degs[tid] : 0;
    if (tid < NN) s_deg[tid] = dg0;
    for (int i = tid; i < MAX_STEPS; i += 1024) s_ny[i] = 0x7fffffff;

    // ---- scan 1: degree prefix -> s_off (CSR offsets)
    scanbuf[0][tid] = dg0;
    __syncthreads();
    int src = 0;
    for (int off = 1; off < 1024; off <<= 1) {
        int v = scanbuf[src][tid];
        if (tid >= off) v += scanbuf[src][tid - off];
        scanbuf[src ^ 1][tid] = v;
        src ^= 1;
        __syncthreads();
    }
    if (tid <= NN) s_off[tid] = scanbuf[src][tid] - ((tid < NN) ? dg0 : 0);
    __syncthreads();

    // ---- scan 2: start-node compaction -> s_nodes, S0
    scanbuf[0][tid] = stt;
    __syncthreads();
    src = 0;
    for (int off = 1; off < 1024; off <<= 1) {
        int v = scanbuf[src][tid];
        if (tid >= off) v += scanbuf[src][tid - off];
        scanbuf[src ^ 1][tid] = v;
        src ^= 1;
        __syncthreads();
    }
    if (stt) s_nodes[scanbuf[src][tid] - 1] = tid;
    const int S0tot = scanbuf[src][1023];
    __syncthreads();

    // ---- stage CSR into LDS; init queue head
    if (tid < NN) {
        const int o = s_off[tid], dg = s_deg[tid];
        for (int e = 0; e < dg; ++e) s_csr[o + e] = g_nbrs64[tid][e];
    }
    const int S0 = (S0tot < MAX_STEPS) ? S0tot : MAX_STEPS;
    int known = S0;
    for (int i = tid; i < known; i += 1024) s_nx[i] = s_nodes[i];
    __syncthreads();

    // ---- round-expansion (message-independent), all in LDS
    for (int round = 0; round < 8 && known > 0; ++round) {
        const int C = (known + 1023) >> 10;
        const int base = tid * C;
        int lsum = 0;
        for (int j = 0; j < C; ++j) {
            int i = base + j;
            if (i < known) lsum += s_deg[s_nx[i]];
        }
        scanbuf[0][tid] = lsum;
        __syncthreads();
        src = 0;
        for (int off = 1; off < 1024; off <<= 1) {
            int v = scanbuf[src][tid];
            if (tid >= off) v += scanbuf[src][tid - off];
            scanbuf[src ^ 1][tid] = v;
            src ^= 1;
            __syncthreads();
        }
        const int excl = (tid == 0) ? 0 : scanbuf[src][tid - 1];
        const int total = scanbuf[src][1023];
        int t = S0 + excl;
        for (int j = 0; j < C; ++j) {
            int i = base + j;
            if (i < known) {
                const int nd = s_nx[i];
                const int dg = s_deg[nd], o = s_off[nd];
                s_ny[i] = t;
                for (int e = 0; e < dg; ++e) {
                    const int pos = t + e;
                    if (pos >= known && pos < MAX_STEPS) s_nx[pos] = s_csr[o + e];
                }
                t += dg;
            }
        }
        __syncthreads();
        int newknown = S0 + total;
        if (newknown > MAX_STEPS) newknown = MAX_STEPS;
        if (newknown == known) break;
        known = newknown;
    }
    __syncthreads();
    const int kn = known;
    if (tid == 0) s_misc[1] = kn;
    __syncthreads();
    for (int i = tid; i < kn; i += 1024)
        if (s_ny[i] <= i) atomicMin(&s_misc[1], i);        // first drained step
    __syncthreads();
    const int istar = s_misc[1];
    if (tid == 0) s_misc[2] = istar;
    __syncthreads();
    for (int i = tid; i < istar; i += 1024)
        if (s_ny[i] >= istar) atomicMin(&s_misc[2], i);    // first nothing-consumed producer
    __syncthreads();
    const int P = s_misc[2];

    // ---- write schedule (coalesced int4)
    for (int i = tid; i < MAX_STEPS; i += 1024) {
        int4 sc;
        if (i < kn) { sc.x = s_nx[i]; sc.y = s_ny[i]; sc.z = s_deg[sc.x]; }
        else { sc.x = 0; sc.y = 0x7fffffff; sc.z = 0; }
        sc.w = 0;
        g_sched[i] = sc;
    }
    if (tid == 0) { g_S0 = S0; g_T = istar; g_P = P; }

    // ---- phase-B per-node counts + offsets (scan 3)
    if (tid < NN) s_cnt[tid] = 0;
    __syncthreads();
    for (int i = P + tid; i < istar; i += 1024) atomicAdd(&s_cnt[s_nx[i]], 1);
    __syncthreads();
    const int cnt0 = (tid < NN) ? s_cnt[tid] : 0;
    scanbuf[0][tid] = cnt0;
    __syncthreads();
    src = 0;
    for (int off = 1; off < 1024; off <<= 1) {
        int v = scanbuf[src][tid];
        if (tid >= off) v += scanbuf[src][tid - off];
        scanbuf[src ^ 1][tid] = v;
        src ^= 1;
        __syncthreads();
    }
    if (tid <= NN) g_noff[tid] = scanbuf[src][tid] - ((tid < NN) ? cnt0 : 0);

    for (int i = tid; i < MAX_STEPS; i += 1024) g_mready[i] = (i < S0) ? 1 : 0;
}

// ---------------- alist/nlist via parallel ballot compaction ----------------
// blocks 0..NN-1: nlist for node b over [P, istar)
// blocks NN..NN+NWGA-1: alist for phase-A WG (b-NN) over [0, P)
__global__ __launch_bounds__(256) void k_lists() {
    __shared__ int sWOff[4];
    __shared__ int sBase;
    const int b = blockIdx.x, tid = threadIdx.x;
    const int lane = tid & 63, wv = tid >> 6;
    if (b < NN) {
        const int v = b;
        const int lo = g_P, hi = g_T;
        if (tid == 0) sBase = g_noff[v];
        __syncthreads();
        for (int st = lo; st < hi; st += 256) {
            const int i = st + tid;
            const bool m = (i < hi) && (g_sched[i].x == v);
            const unsigned long long bal = __ballot(m);
            const int rank = __popcll(bal & ((1ull << lane) - 1ull));
            if (lane == 0) sWOff[wv] = __popcll(bal);
            __syncthreads();
            if (tid == 0) {
                int acc = sBase;
                for (int w = 0; w < 4; ++w) { const int t = sWOff[w]; sWOff[w] = acc; acc += t; }
                sBase = acc;
            }
            __syncthreads();
            if (m) g_nlist[sWOff[wv] + rank] = i;
            __syncthreads();
        }
    } else {
        const int w0 = b - NN;
        const int hi = g_P;
        if (tid == 0) sBase = 0;
        __syncthreads();
        for (int st = 0; st < hi; st += 256) {
            const int i = st + tid;
            const bool m = (i < hi) && ((g_sched[i].x & (NWGA - 1)) == w0);
            const unsigned long long bal = __ballot(m);
            const int rank = __popcll(bal & ((1ull << lane) - 1ull));
            if (lane == 0) sWOff[wv] = __popcll(bal);
            __syncthreads();
            if (tid == 0) {
                int acc = sBase;
                for (int w = 0; w < 4; ++w) { const int t = sWOff[w]; sWOff[w] = acc; acc += t; }
                sBase = acc;
            }
            __syncthreads();
            if (m) g_alist[w0][sWOff[wv] + rank] = i;
            __syncthreads();
        }
        if (tid == 0) g_acnt[w0] = sBase;
    }
}

// ---------------- initial queue messages ----------------
__global__ __launch_bounds__(128) void k_qinit(const float* __restrict__ first_message) {
    const int i = blockIdx.x;
    if (i >= g_S0) return;
    const int node = g_sched[i].x;
    g_qmsgs[i][threadIdx.x] = first_message[node * MSGD + threadIdx.x];
}

// ---------------- phase A: fence-free dataflow over steps [0, P) ----------------
__global__ __launch_bounds__(512, 1) void k_phaseA(const float* __restrict__ nm_b) {
    __shared__ float sAct[MSGD];
    __shared__ float sNH[2][HID], sNC[2][HID];
    __shared__ float sGates[1024];
    __shared__ float sPart[4 * MSGD];
    __shared__ unsigned int sActP[192];    // gate acts packed: [msg(64) | h(128)] pairs
    __shared__ unsigned int sActN[192];    // nm acts packed:   [h(128) | msg(64)] pairs
    const int tid = threadIdx.x, wg = blockIdx.x;
    const int cntA = g_acnt[wg];
    if (cntA == 0) return;
    const int S0 = g_S0, T = g_T;
    const float vb0 = g_bias[2 * tid], vb1 = g_bias[2 * tid + 1];

    for (int idx = tid; idx < 2 * HID; idx += 512) {
        int sl = idx >> 8, u = idx & 255, v = wg + (sl << 8);
        sNH[sl][u] = g_hid[v][u];
        sNC[sl][u] = g_cell[v][u];
    }
    __syncthreads();

    for (int k = 0; k < cntA; ++k) {
        const int s = g_alist[wg][k];
        const int4 sc = g_sched[s];
        const int node = sc.x, y = sc.y, deg = sc.z, sl = node >> 8;
        if (s >= S0) {
            if (tid == 0) {
                while (__hip_atomic_load(&g_mready[s], __ATOMIC_RELAXED,
                                         __HIP_MEMORY_SCOPE_AGENT) == 0)
                    __builtin_amdgcn_s_sleep(2);
            }
            __syncthreads();
            __builtin_amdgcn_fence(__ATOMIC_ACQUIRE, "workgroup");
        }
        // stage message + pack; pack h_prev
        if (tid < 64) {
            float a0, a1;
            if (s < S0) { a0 = g_qmsgs[s][2 * tid]; a1 = g_qmsgs[s][2 * tid + 1]; }
            else {
                a0 = __hip_atomic_load(&g_qmsgs[s][2 * tid],     __ATOMIC_RELAXED,
                                       __HIP_MEMORY_SCOPE_AGENT);
                a1 = __hip_atomic_load(&g_qmsgs[s][2 * tid + 1], __ATOMIC_RELAXED,
                                       __HIP_MEMORY_SCOPE_AGENT);
            }
            sAct[2 * tid] = a0; sAct[2 * tid + 1] = a1;
            sActP[tid] = pkh(a0, a1);
        } else if (tid < 192) {
            const int j = tid - 64;
            sActP[tid] = pkh(sNH[sl][2 * j], sNH[sl][2 * j + 1]);
        }
        __syncthreads();
        // gates: rows (2t, 2t+1), 96 x uint4 f16 tiles
        {
            float acc0 = vb0, acc1 = vb1;
#pragma unroll 8
            for (int q = 0; q < 96; ++q) {
                const uint4 w = g_WTph[q * 512 + tid];
                const unsigned int a01 = sActP[2 * q], a23 = sActP[2 * q + 1];
                acc0 = fdot2u(w.x, a01, acc0); acc1 = fdot2u(w.y, a01, acc1);
                acc0 = fdot2u(w.z, a23, acc0); acc1 = fdot2u(w.w, a23, acc1);
            }
            ((float2*)sGates)[tid] = make_float2(acc0, acc1);
        }
        __syncthreads();
        // LSTM cell (torch order i,f,g,o)
        if (tid < HID) {
            const int u = tid;
            const float gi = sGates[u], gf = sGates[256 + u];
            const float gg = sGates[512 + u], go = sGates[768 + u];
            const float cp = sNC[sl][u];
            const float cn = sigm(gf) * cp + sigm(gi) * tanhf(gg);
            const float hn = sigm(go) * tanhf(cn);
            sNC[sl][u] = cn;
            sNH[sl][u] = hn;
        }
        __syncthreads();
        // pack nm acts: [h_new(256) | msg(128)]
        if (tid < 128) sActN[tid] = pkh(sNH[sl][2 * tid], sNH[sl][2 * tid + 1]);
        else if (tid < 192) {
            const int j = tid - 128;
            sActN[tid] = pkh(sAct[2 * j], sAct[2 * j + 1]);
        }
        __syncthreads();
        // nm partials: o = tid&127, col-quarter cq = tid>>7 covers 48 pairs
        {
            const int o = tid & (MSGD - 1), cq = tid >> 7;
            float p = 0.0f;
#pragma unroll 8
            for (int j = 0; j < 48; ++j) {
                const int cp = 48 * cq + j;
                p = fdot2u(g_nmTph[cp * 128 + o], sActN[cp], p);
            }
            sPart[cq * MSGD + o] = p;
        }
        __syncthreads();
        const int lim = (y + deg <= T) ? deg : (T - y);
        if (tid < MSGD) {
            const float m = nm_b[tid] + sPart[tid] + sPart[MSGD + tid]
                          + sPart[2 * MSGD + tid] + sPart[3 * MSGD + tid];
            for (int e = 0; e < lim; ++e)
                __hip_atomic_store(&g_qmsgs[y + e][tid], m, __ATOMIC_RELAXED,
                                   __HIP_MEMORY_SCOPE_AGENT);
        }
        __syncthreads();   // drain all waves' stores before flags
        if (tid < lim)
            __hip_atomic_store(&g_mready[y + tid], 1, __ATOMIC_RELAXED,
                               __HIP_MEMORY_SCOPE_AGENT);
    }
    __syncthreads();
    for (int idx = tid; idx < 2 * HID; idx += 512) {
        int sl = idx >> 8, u = idx & 255, v = wg + (sl << 8);
        g_hid[v][u]  = sNH[sl][u];
        g_cell[v][u] = sNC[sl][u];
    }
}

// ---------------- phase B: one WG per node, serial chain, f16 gate stream ----------------
__global__ __launch_bounds__(512, 4) void k_phaseB() {
    __shared__ float sGates[1024];
    __shared__ float sH[HID], sC[HID];
    __shared__ unsigned int sActP[192];
    const int n = blockIdx.x, tid = threadIdx.x;
    int pos = g_noff[n];
    const int pend = g_noff[n + 1];
    if (pos >= pend) return;
    const float vb0 = g_bias[2 * tid], vb1 = g_bias[2 * tid + 1];

    if (tid < HID) { sH[tid] = g_hid[n][tid]; sC[tid] = g_cell[n][tid]; }
    __syncthreads();

    for (; pos < pend; ++pos) {
        const int s = g_nlist[pos];
        if (tid < 64) {
            const float2 m = *(const float2*)&g_qmsgs[s][2 * tid];
            sActP[tid] = pkh(m.x, m.y);
        } else if (tid < 192) {
            const int j = tid - 64;
            sActP[tid] = pkh(sH[2 * j], sH[2 * j + 1]);
        }
        __syncthreads();
        float acc0 = vb0, acc1 = vb1;
#pragma unroll 8
        for (int q = 0; q < 96; ++q) {
            const uint4 w = g_WTph[q * 512 + tid];
            const unsigned int a01 = sActP[2 * q], a23 = sActP[2 * q + 1];
            acc0 = fdot2u(w.x, a01, acc0); acc1 = fdot2u(w.y, a01, acc1);
            acc0 = fdot2u(w.z, a23, acc0); acc1 = fdot2u(w.w, a23, acc1);
        }
        ((float2*)sGates)[tid] = make_float2(acc0, acc1);
        __syncthreads();
        if (tid < HID) {
            const float gi = sGates[tid], gf = sGates[256 + tid];
            const float gg = sGates[512 + tid], go = sGates[768 + tid];
            const float cn = sigm(gf) * sC[tid] + sigm(gi) * tanhf(gg);
            sC[tid] = cn;
            sH[tid] = sigm(go) * tanhf(cn);
        }
        __syncthreads();
    }
    if (tid < HID) g_hid[n][tid] = sH[tid];
}

// ---------------- decoder: logits + log_softmax ----------------
__global__ __launch_bounds__(256) void k_decode(const float* __restrict__ dec_W,
                                                const float* __restrict__ dec_b,
                                                float* __restrict__ out) {
    const int gtid = blockIdx.x * 256 + threadIdx.x;
    const int row = gtid >> 4, lane = gtid & 15;   // row = p*NN + n
    const int p = row >> 9, n = row & (NN - 1);
    const float* dw = dec_W + (p * OUTC + lane) * HID;
    float acc = dec_b[p * OUTC + lane];
#pragma unroll 8
    for (int j = 0; j < HID; j += 4) {
        const float4 hv = *(const float4*)&g_hid[n][j];
        const float4 wv = *(const float4*)(dw + j);
        acc += hv.x * wv.x + hv.y * wv.y + hv.z * wv.z + hv.w * wv.w;
    }
    float mx = acc;
    mx = fmaxf(mx, __shfl_xor(mx, 1));
    mx = fmaxf(mx, __shfl_xor(mx, 2));
    mx = fmaxf(mx, __shfl_xor(mx, 4));
    mx = fmaxf(mx, __shfl_xor(mx, 8));
    float s = expf(acc - mx);
    s += __shfl_xor(s, 1);
    s += __shfl_xor(s, 2);
    s += __shfl_xor(s, 4);
    s += __shfl_xor(s, 8);
    out[row * OUTC + lane] = acc - mx - logf(s);
}

extern "C" void kernel_launch(void* const* d_in, const int* in_sizes, int n_in,
                              void* d_out, int out_size, void* d_ws, size_t ws_size,
                              hipStream_t stream) {
    (void)in_sizes; (void)n_in; (void)out_size; (void)d_ws; (void)ws_size;
    const float* xa   = (const float*)d_in[0];
    const float* fm   = (const float*)d_in[1];
    const int*   ei   = (const int*)d_in[2];
    const int*   st   = (const int*)d_in[3];
    const float* encW = (const float*)d_in[4];
    const float* encb = (const float*)d_in[5];
    const float* Wih  = (const float*)d_in[6];
    const float* Whh  = (const float*)d_in[7];
    const float* bih  = (const float*)d_in[8];
    const float* bhh  = (const float*)d_in[9];
    const float* nmW  = (const float*)d_in[10];
    const float* nmb  = (const float*)d_in[11];
    const float* decW = (const float*)d_in[12];
    const float* decb = (const float*)d_in[13];
    float* out = (float*)d_out;

    hipLaunchKernelGGL(k_encoder, dim3(512),       dim3(256),  0, stream, xa, encW, encb);
    hipLaunchKernelGGL(k_prep,    dim3(512),       dim3(256),  0, stream, Wih, Whh, bih, bhh, nmW);
    hipLaunchKernelGGL(k_nbr,     dim3(NN),        dim3(256),  0, stream, ei);
    hipLaunchKernelGGL(k_sched,   dim3(1),         dim3(1024), 0, stream, st);
    hipLaunchKernelGGL(k_lists,   dim3(NN + NWGA), dim3(256),  0, stream);
    hipLaunchKernelGGL(k_qinit,   dim3(512),       dim3(128),  0, stream, fm);
    hipLaunchKernelGGL(k_phaseA,  dim3(NWGA),      dim3(512),  0, stream, nmb);
    hipLaunchKernelGGL(k_phaseB,  dim3(NN),        dim3(512),  0, stream);
    hipLaunchKernelGGL(k_decode,  dim3(128),       dim3(256),  0, stream, decW, decb, out);
}